// Round 1
// baseline (8048.715 us; speedup 1.0000x reference)
//
#include <hip/hip_runtime.h>
#include <math.h>

#define NT 730
#define NS 2000
#define NH 16
#define NG 32
#define NR 15
#define HID 256

#define K2_ROWS 16
#define K2_PITCH 260   // floats; 260%32==4 -> conflict-free b128 reads across 4 r-groups; 260*4B is 16B-aligned

__device__ __forceinline__ float fast_tanh(float x) {
    float e = __expf(2.f * x);
    return 1.f - 2.f / (e + 1.f);   // exact +-1 saturation at |x| large
}
__device__ __forceinline__ float sigmoidf_(float x) { return 1.f / (1.f + __expf(-x)); }
__device__ __forceinline__ float hsigf(float x) { return fminf(fmaxf(x * (1.f / 6.f) + 0.5f, 0.f), 1.f); }

// ---------------------------------------------------------------------------
// k_pack: gather small weight slices into coalesced layouts.
//   A1[k]  = fcT1_W1[k][0]           (LAI column)
//   C0..C2 = fcT2_W1[k][0..2]        (R, T1, T2 columns)
//   W2C[c][k], c in [0,48): rows 0..31 = fcT1_W2, rows 32..47 = fcT2_W2[0..15]
// ---------------------------------------------------------------------------
__global__ __launch_bounds__(256) void k_pack(
    const float* __restrict__ T1W1, const float* __restrict__ T2W1,
    const float* __restrict__ T1W2, const float* __restrict__ T2W2,
    float* __restrict__ A1, float* __restrict__ C0, float* __restrict__ C1,
    float* __restrict__ C2, float* __restrict__ W2C)
{
    int k = threadIdx.x;
    A1[k] = T1W1[k * (1 + NG)];
    C0[k] = T2W1[k * (3 + NG)];
    C1[k] = T2W1[k * (3 + NG) + 1];
    C2[k] = T2W1[k * (3 + NG) + 2];
    for (int c = 0; c < 48; ++c)
        W2C[c * HID + k] = (c < 32) ? T1W2[c * HID + k] : T2W2[(c - 32) * HID + k];
}

// ---------------------------------------------------------------------------
// k_basin: per-basin MLPs + derived params.
//   P8[s*16+h][8]   = {k1,k2,k23,k3,gl,qb,ge1,ge2}
//   RKGA[s*16+h][16]= ga[s,h] * relu(wR[s, h*15 + (14-d)])  (conv tap at delay d)
//   BASE1/BASE2[s][256] = xc-part of fcT1/fcT2 first layer (+bias)
// ---------------------------------------------------------------------------
__global__ __launch_bounds__(256) void k_basin(
    const float* __restrict__ XC,
    const float* __restrict__ fcW1, const float* __restrict__ fcb1,
    const float* __restrict__ fcW2, const float* __restrict__ fcb2,
    const float* __restrict__ fRW1, const float* __restrict__ fRb1,
    const float* __restrict__ fRW2, const float* __restrict__ fRb2,
    const float* __restrict__ T1W1, const float* __restrict__ T1b1,
    const float* __restrict__ T2W1, const float* __restrict__ T2b1,
    float* __restrict__ P8, float* __restrict__ RKGA,
    float* __restrict__ BASE1, float* __restrict__ BASE2)
{
    int s = blockIdx.x, tid = threadIdx.x;
    __shared__ float xcs[NG];
    __shared__ float h[HID], hR[HID];
    __shared__ float wbuf[10 * NH], wRbuf[NH * NR];
    __shared__ float gav[NH];

    if (tid < NG) xcs[tid] = XC[s * NG + tid];
    __syncthreads();

    // hidden layers (k = tid)
    {
        float a = fcb1[tid], aR = fRb1[tid];
        const float4* w4  = (const float4*)(fcW1 + tid * NG);
        const float4* wR4 = (const float4*)(fRW1 + tid * NG);
        const float4* x4  = (const float4*)xcs;
#pragma unroll
        for (int g = 0; g < NG / 4; ++g) {
            float4 xv = x4[g], wv = w4[g], rv = wR4[g];
            a  += xv.x * wv.x + xv.y * wv.y + xv.z * wv.z + xv.w * wv.w;
            aR += xv.x * rv.x + xv.y * rv.y + xv.z * rv.z + xv.w * rv.w;
        }
        h[tid] = fast_tanh(a);
        hR[tid] = fast_tanh(aR);
    }
    // bases for the big MLPs (k = tid)
    {
        float b1 = T1b1[tid], b2 = T2b1[tid];
        const float* w1 = T1W1 + tid * (1 + NG) + 1;
        const float* w2 = T2W1 + tid * (3 + NG) + 3;
#pragma unroll 8
        for (int g = 0; g < NG; ++g) { float xv = xcs[g]; b1 += xv * w1[g]; b2 += xv * w2[g]; }
        BASE1[(size_t)s * HID + tid] = b1;
        BASE2[(size_t)s * HID + tid] = b2;
    }
    __syncthreads();

    if (tid < 10 * NH) {
        float a = fcb2[tid];
        const float4* w4 = (const float4*)(fcW2 + tid * HID);
        const float4* h4 = (const float4*)h;
        for (int k = 0; k < HID / 4; ++k) {
            float4 hv = h4[k], wv = w4[k];
            a += hv.x * wv.x + hv.y * wv.y + hv.z * wv.z + hv.w * wv.w;
        }
        wbuf[tid] = a;
    }
    if (tid < NH * NR) {
        float a = fRb2[tid];
        const float4* w4 = (const float4*)(fRW2 + tid * HID);
        const float4* h4 = (const float4*)hR;
        for (int k = 0; k < HID / 4; ++k) {
            float4 hv = h4[k], wv = w4[k];
            a += hv.x * wv.x + hv.y * wv.y + hv.z * wv.z + hv.w * wv.w;
        }
        wRbuf[tid] = a;
    }
    __syncthreads();

    if (tid < NH) {
        int hh = tid;
        float mx = -1e30f;
        for (int i = 0; i < NH; ++i) mx = fmaxf(mx, wbuf[6 * NH + i]);
        float sum = 0.f;
        for (int i = 0; i < NH; ++i) sum += expf(wbuf[6 * NH + i] - mx);
        gav[hh] = expf(wbuf[6 * NH + hh] - mx) / sum;

        float* p = P8 + (size_t)(s * NH + hh) * 8;
        p[0] = sigmoidf_(wbuf[1 * NH + hh]);          // k1
        p[1] = sigmoidf_(wbuf[2 * NH + hh]);          // k2
        p[2] = sigmoidf_(wbuf[3 * NH + hh]);          // k23
        p[3] = sigmoidf_(wbuf[4 * NH + hh]) * 0.1f;   // k3
        p[4] = expf(wbuf[5 * NH + hh]) * 2.f;         // gl
        p[5] = fmaxf(wbuf[7 * NH + hh], 0.f);         // qb
        p[6] = fmaxf(wbuf[8 * NH + hh], 0.f);         // ge1
        p[7] = fmaxf(wbuf[9 * NH + hh], 0.f);         // ge2
    }
    __syncthreads();

    if (tid < NH * NR) {
        int hh = tid / NR, j = tid % NR;
        // conv tap at delay d corresponds to kernel index nr-1-d (cross-correlation, left pad)
        RKGA[(size_t)(s * NH + hh) * 16 + (NR - 1 - j)] = gav[hh] * fmaxf(wRbuf[hh * NR + j], 0.f);
    }
}

// ---------------------------------------------------------------------------
// k_mlp: per-(t,s) big MLPs -> vi,vk (u16-packed), vm; plus vp/Ps/Pl/E pack.
//   Block: 256 threads, one t, 16 consecutive s.
//   Phase 1: h1[r][k] = tanh(base1 + LAI*a1), h2[r][k] = tanh(base2 + R*c0 + T1*c1 + T2*c2)
//   Phase 2: 48-col GEMM from LDS; thread = (r = tid>>4, cg = tid&15), cols {cg, cg+16, 32+cg}
// ---------------------------------------------------------------------------
__global__ __launch_bounds__(256) void k_mlp(
    const float* __restrict__ X,
    const float* __restrict__ BASE1, const float* __restrict__ BASE2,
    const float* __restrict__ A1, const float* __restrict__ C0,
    const float* __restrict__ C1, const float* __restrict__ C2,
    const float* __restrict__ W2C,
    const float* __restrict__ T1b2, const float* __restrict__ T2b2,
    unsigned* __restrict__ VIK, float* __restrict__ VM, float4* __restrict__ PSE)
{
    int tid = threadIdx.x;
    int s0 = blockIdx.x * K2_ROWS;
    int t = blockIdx.y;

    __shared__ float h1s[K2_ROWS][K2_PITCH];
    __shared__ float h2s[K2_ROWS][K2_PITCH];
    __shared__ float xrow[K2_ROWS][6];

    if (tid < K2_ROWS * 6)
        ((float*)xrow)[tid] = X[((size_t)t * NS + s0) * 6 + tid];
    __syncthreads();

    if (tid < K2_ROWS) {
        float P = xrow[tid][0], E = xrow[tid][1], T1 = xrow[tid][2], T2 = xrow[tid][3];
        float den = T2 - T1;
        float ratio = (T1 + T2) / ((den == 0.f) ? 1.f : den);
        ratio = fminf(fmaxf(ratio, -1.f), 1.f);
        if ((T1 >= 0.f) || (T2 <= 0.f)) ratio = 0.f;
        float vp = 1.f - acosf(ratio) * (1.f / 3.1415f);
        if (T1 >= 0.f) vp = 1.f;
        if (T2 <= 0.f) vp = 0.f;
        PSE[(size_t)t * NS + s0 + tid] = make_float4(P * (1.f - vp), P * vp, E, 0.f);
    }

    float a1v = A1[tid], c0v = C0[tid], c1v = C1[tid], c2v = C2[tid];
    for (int r = 0; r < K2_ROWS; ++r) {
        int s = s0 + r;
        float b1 = BASE1[(size_t)s * HID + tid];
        float b2 = BASE2[(size_t)s * HID + tid];
        float lai = xrow[r][5], R = xrow[r][4], T1 = xrow[r][2], T2 = xrow[r][3];
        h1s[r][tid] = fast_tanh(b1 + lai * a1v);
        h2s[r][tid] = fast_tanh(b2 + R * c0v + T1 * c1v + T2 * c2v);
    }
    __syncthreads();

    int r = tid >> 4, cg = tid & 15;
    float acc0 = T1b2[cg];        // v1 col cg      -> vi
    float acc1 = T1b2[NH + cg];   // v1 col 16+cg   -> vk
    float acc2 = T2b2[cg];        // v2 col cg      -> vm (pre-exp)
    const float4* h1p = (const float4*)&h1s[r][0];
    const float4* h2p = (const float4*)&h2s[r][0];
    const float4* w0p = (const float4*)(W2C + (size_t)cg * HID);
    const float4* w1p = (const float4*)(W2C + (size_t)(NH + cg) * HID);
    const float4* w2p = (const float4*)(W2C + (size_t)(2 * NH + cg) * HID);
#pragma unroll 8
    for (int k = 0; k < HID / 4; ++k) {
        float4 hv1 = h1p[k], hv2 = h2p[k];
        float4 w0 = w0p[k], w1 = w1p[k], w2 = w2p[k];
        acc0 += hv1.x * w0.x + hv1.y * w0.y + hv1.z * w0.z + hv1.w * w0.w;
        acc1 += hv1.x * w1.x + hv1.y * w1.y + hv1.z * w1.z + hv1.w * w1.w;
        acc2 += hv2.x * w2.x + hv2.y * w2.y + hv2.z * w2.z + hv2.w * w2.w;
    }

    float vi = hsigf(acc0);
    float vk = hsigf(acc1);
    size_t o = ((size_t)t * NS + s0 + r) * NH + cg;
    VIK[o] = (unsigned)(vi * 65535.f + 0.5f) | ((unsigned)(vk * 65535.f + 0.5f) << 16);
    VM[o] = __expf(2.f * acc2);
}

// ---------------------------------------------------------------------------
// k_scan: sequential 730-step bucket scan, fused causal conv (taps*ga) + h-sum.
//   One wave = 4 basins x 16 buckets. lane = (s_local<<4) | h.
// ---------------------------------------------------------------------------
__global__ __launch_bounds__(64) void k_scan(
    const unsigned* __restrict__ VIK, const float* __restrict__ VM,
    const float4* __restrict__ PSE, const float* __restrict__ P8,
    const float* __restrict__ RKGA, float* __restrict__ OUT)
{
    int lane = threadIdx.x;
    int s = blockIdx.x * 4 + (lane >> 4);
    int hh = lane & 15;
    int ch = s * NH + hh;

    const float4* pp = (const float4*)(P8 + (size_t)ch * 8);
    float4 pa = pp[0], pb = pp[1];
    float k1 = pa.x, k2 = pa.y, k23 = pa.z, k3 = pa.w;
    float gl = pb.x, qb = pb.y, ge1 = pb.z, ge2 = pb.w;

    float rk[16];
    {
        const float4* rp = (const float4*)(RKGA + (size_t)ch * 16);
#pragma unroll
        for (int i = 0; i < 4; ++i) {
            float4 v = rp[i];
            rk[4 * i] = v.x; rk[4 * i + 1] = v.y; rk[4 * i + 2] = v.z; rk[4 * i + 3] = v.w;
        }
    }

    float S0 = 0.f, Sv = 0.f, S2 = 0.f, S3 = 0.f;
    float q[14];
#pragma unroll
    for (int i = 0; i < 14; ++i) q[i] = 0.f;

    unsigned vik_c = VIK[ch];
    float vm_c = VM[ch];
    float4 pse_c = PSE[s];

    for (int t = 0; t < NT; ++t) {
        int t2 = (t + 1 < NT) ? (t + 1) : t;
        size_t o = (size_t)t2 * NS * NH + ch;
        unsigned vik_n = VIK[o];
        float vm_n = VM[o];
        float4 pse_n = PSE[(size_t)t2 * NS + s];

        float vi = (float)(vik_c & 0xffffu) * (1.f / 65535.f);
        float vk = (float)(vik_c >> 16) * (1.f / 65535.f);
        float Ps = pse_c.x, Pl = pse_c.y, E = pse_c.z;

        float H0 = S0 + Ps;
        float qSm = fminf(H0, vm_c);
        S0 = H0 - qSm;
        float Hv = fmaxf(Sv + Pl * (1.f - vi) - E * ge1, 0.f);
        float qv = Sv * vk;
        Sv = Hv - qv;
        float H2 = fmaxf(S2 + qSm + qv - E * ge2 + Pl * vi, 0.f);
        float x1 = H2 - gl;
        float Q1 = (x1 > 0.f) ? __expf(k1 * __logf(x1)) : 0.f;
        float q2 = fminf(H2, gl) * k2;
        float Q2 = q2 * (1.f - k23);
        float H3 = S3 + q2 * k23;
        float Q3 = H3 * k3 + qb;
        S2 = H2 - Q1 - q2;
        S3 = H3 - Q3;
        float qt = Q1 + Q2 + Q3;

        float y = qt * rk[0];
#pragma unroll
        for (int d = 1; d <= 14; ++d) y += q[d - 1] * rk[d];
#pragma unroll
        for (int i = 13; i > 0; --i) q[i] = q[i - 1];
        q[0] = qt;

        y += __shfl_xor(y, 1);
        y += __shfl_xor(y, 2);
        y += __shfl_xor(y, 4);
        y += __shfl_xor(y, 8);
        if (hh == 0) OUT[(size_t)t * NS + s] = y;

        vik_c = vik_n; vm_c = vm_n; pse_c = pse_n;
    }
}

// ---------------------------------------------------------------------------
extern "C" void kernel_launch(void* const* d_in, const int* in_sizes, int n_in,
                              void* d_out, int out_size, void* d_ws, size_t ws_size,
                              hipStream_t stream)
{
    const float* X    = (const float*)d_in[0];
    const float* XC   = (const float*)d_in[1];
    const float* fcW1 = (const float*)d_in[2];
    const float* fcb1 = (const float*)d_in[3];
    const float* fcW2 = (const float*)d_in[4];
    const float* fcb2 = (const float*)d_in[5];
    const float* fRW1 = (const float*)d_in[6];
    const float* fRb1 = (const float*)d_in[7];
    const float* fRW2 = (const float*)d_in[8];
    const float* fRb2 = (const float*)d_in[9];
    const float* T1W1 = (const float*)d_in[10];
    const float* T1b1 = (const float*)d_in[11];
    const float* T1W2 = (const float*)d_in[12];
    const float* T1b2 = (const float*)d_in[13];
    const float* T2W1 = (const float*)d_in[14];
    const float* T2b1 = (const float*)d_in[15];
    const float* T2W2 = (const float*)d_in[16];
    const float* T2b2 = (const float*)d_in[17];
    float* OUT = (float*)d_out;

    char* w = (char*)d_ws;
    unsigned* VIK = (unsigned*)w;  w += (size_t)NT * NS * NH * 4;   // 93.44 MB
    float* VM    = (float*)w;      w += (size_t)NT * NS * NH * 4;   // 93.44 MB
    float4* PSE  = (float4*)w;     w += (size_t)NT * NS * 16;       // 23.36 MB
    float* BASE1 = (float*)w;      w += (size_t)NS * HID * 4;
    float* BASE2 = (float*)w;      w += (size_t)NS * HID * 4;
    float* P8    = (float*)w;      w += (size_t)NS * NH * 8 * 4;
    float* RKGA  = (float*)w;      w += (size_t)NS * NH * 16 * 4;
    float* W2C   = (float*)w;      w += 48 * HID * 4;
    float* A1    = (float*)w;      w += HID * 4;
    float* C0    = (float*)w;      w += HID * 4;
    float* C1    = (float*)w;      w += HID * 4;
    float* C2    = (float*)w;      w += HID * 4;
    (void)ws_size; (void)in_sizes; (void)n_in; (void)out_size;

    k_pack<<<dim3(1), dim3(256), 0, stream>>>(T1W1, T2W1, T1W2, T2W2, A1, C0, C1, C2, W2C);
    k_basin<<<dim3(NS), dim3(256), 0, stream>>>(XC, fcW1, fcb1, fcW2, fcb2,
                                                fRW1, fRb1, fRW2, fRb2,
                                                T1W1, T1b1, T2W1, T2b1,
                                                P8, RKGA, BASE1, BASE2);
    k_mlp<<<dim3(NS / K2_ROWS, NT), dim3(256), 0, stream>>>(X, BASE1, BASE2, A1, C0, C1, C2,
                                                            W2C, T1b2, T2b2, VIK, VM, PSE);
    k_scan<<<dim3(NS / 4), dim3(64), 0, stream>>>(VIK, VM, PSE, P8, RKGA, OUT);
}

// Round 2
// 1179.958 us; speedup vs baseline: 6.8212x; 6.8212x over previous
//
#include <hip/hip_runtime.h>
#include <math.h>

#define NT 730
#define NS 2000
#define NH 16
#define NG 32
#define NR 15
#define HID 256

typedef _Float16 f16x8 __attribute__((ext_vector_type(8)));
typedef float f32x4 __attribute__((ext_vector_type(4)));

__device__ __forceinline__ float fast_tanh(float x) {
    float e = __expf(2.f * x);
    return 1.f - 2.f / (e + 1.f);
}
__device__ __forceinline__ float sigmoidf_(float x) { return 1.f / (1.f + __expf(-x)); }
__device__ __forceinline__ float hsigf(float x) { return fminf(fmaxf(x * (1.f / 6.f) + 0.5f, 0.f), 1.f); }

// ---------------------------------------------------------------------------
// k_pack: gather small weight slices into coalesced layouts.
//   A1[k]  = fcT1_W1[k][0] (LAI col);  C0..C2[k] = fcT2_W1[k][0..2] (R,T1,T2)
//   W2H[c][k] fp16, c in [0,48): rows 0..31 = fcT1_W2, 32..47 = fcT2_W2[0..15]
//   (B^T layout: lane n=c reads 8 consecutive k -> direct f16x8 B-fragment)
// ---------------------------------------------------------------------------
__global__ __launch_bounds__(256) void k_pack(
    const float* __restrict__ T1W1, const float* __restrict__ T2W1,
    const float* __restrict__ T1W2, const float* __restrict__ T2W2,
    float* __restrict__ A1, float* __restrict__ C0, float* __restrict__ C1,
    float* __restrict__ C2, _Float16* __restrict__ W2H)
{
    int k = threadIdx.x;
    A1[k] = T1W1[k * (1 + NG)];
    C0[k] = T2W1[k * (3 + NG)];
    C1[k] = T2W1[k * (3 + NG) + 1];
    C2[k] = T2W1[k * (3 + NG) + 2];
    for (int c = 0; c < 48; ++c)
        W2H[c * HID + k] = (_Float16)((c < 32) ? T1W2[c * HID + k] : T2W2[(c - 32) * HID + k]);
}

// ---------------------------------------------------------------------------
// k_basin: per-basin MLPs + derived params (unchanged from R1).
// ---------------------------------------------------------------------------
__global__ __launch_bounds__(256) void k_basin(
    const float* __restrict__ XC,
    const float* __restrict__ fcW1, const float* __restrict__ fcb1,
    const float* __restrict__ fcW2, const float* __restrict__ fcb2,
    const float* __restrict__ fRW1, const float* __restrict__ fRb1,
    const float* __restrict__ fRW2, const float* __restrict__ fRb2,
    const float* __restrict__ T1W1, const float* __restrict__ T1b1,
    const float* __restrict__ T2W1, const float* __restrict__ T2b1,
    float* __restrict__ P8, float* __restrict__ RKGA,
    float* __restrict__ BASE1, float* __restrict__ BASE2)
{
    int s = blockIdx.x, tid = threadIdx.x;
    __shared__ float xcs[NG];
    __shared__ float h[HID], hR[HID];
    __shared__ float wbuf[10 * NH], wRbuf[NH * NR];
    __shared__ float gav[NH];

    if (tid < NG) xcs[tid] = XC[s * NG + tid];
    __syncthreads();

    {
        float a = fcb1[tid], aR = fRb1[tid];
        const float4* w4  = (const float4*)(fcW1 + tid * NG);
        const float4* wR4 = (const float4*)(fRW1 + tid * NG);
        const float4* x4  = (const float4*)xcs;
#pragma unroll
        for (int g = 0; g < NG / 4; ++g) {
            float4 xv = x4[g], wv = w4[g], rv = wR4[g];
            a  += xv.x * wv.x + xv.y * wv.y + xv.z * wv.z + xv.w * wv.w;
            aR += xv.x * rv.x + xv.y * rv.y + xv.z * rv.z + xv.w * rv.w;
        }
        h[tid] = fast_tanh(a);
        hR[tid] = fast_tanh(aR);
    }
    {
        float b1 = T1b1[tid], b2 = T2b1[tid];
        const float* w1 = T1W1 + tid * (1 + NG) + 1;
        const float* w2 = T2W1 + tid * (3 + NG) + 3;
#pragma unroll 8
        for (int g = 0; g < NG; ++g) { float xv = xcs[g]; b1 += xv * w1[g]; b2 += xv * w2[g]; }
        BASE1[(size_t)s * HID + tid] = b1;
        BASE2[(size_t)s * HID + tid] = b2;
    }
    __syncthreads();

    if (tid < 10 * NH) {
        float a = fcb2[tid];
        const float4* w4 = (const float4*)(fcW2 + tid * HID);
        const float4* h4 = (const float4*)h;
        for (int k = 0; k < HID / 4; ++k) {
            float4 hv = h4[k], wv = w4[k];
            a += hv.x * wv.x + hv.y * wv.y + hv.z * wv.z + hv.w * wv.w;
        }
        wbuf[tid] = a;
    }
    if (tid < NH * NR) {
        float a = fRb2[tid];
        const float4* w4 = (const float4*)(fRW2 + tid * HID);
        const float4* h4 = (const float4*)hR;
        for (int k = 0; k < HID / 4; ++k) {
            float4 hv = h4[k], wv = w4[k];
            a += hv.x * wv.x + hv.y * wv.y + hv.z * wv.z + hv.w * wv.w;
        }
        wRbuf[tid] = a;
    }
    __syncthreads();

    if (tid < NH) {
        int hh = tid;
        float mx = -1e30f;
        for (int i = 0; i < NH; ++i) mx = fmaxf(mx, wbuf[6 * NH + i]);
        float sum = 0.f;
        for (int i = 0; i < NH; ++i) sum += expf(wbuf[6 * NH + i] - mx);
        gav[hh] = expf(wbuf[6 * NH + hh] - mx) / sum;

        float* p = P8 + (size_t)(s * NH + hh) * 8;
        p[0] = sigmoidf_(wbuf[1 * NH + hh]);
        p[1] = sigmoidf_(wbuf[2 * NH + hh]);
        p[2] = sigmoidf_(wbuf[3 * NH + hh]);
        p[3] = sigmoidf_(wbuf[4 * NH + hh]) * 0.1f;
        p[4] = expf(wbuf[5 * NH + hh]) * 2.f;
        p[5] = fmaxf(wbuf[7 * NH + hh], 0.f);
        p[6] = fmaxf(wbuf[8 * NH + hh], 0.f);
        p[7] = fmaxf(wbuf[9 * NH + hh], 0.f);
    }
    __syncthreads();

    if (tid < NH * NR) {
        int hh = tid / NR, j = tid % NR;
        RKGA[(size_t)(s * NH + hh) * 16 + (NR - 1 - j)] = gav[hh] * fmaxf(wRbuf[hh * NR + j], 0.f);
    }
}

// ---------------------------------------------------------------------------
// k_pse: vp partition -> (Ps, Pl, E) per (t,s).
// ---------------------------------------------------------------------------
__global__ __launch_bounds__(256) void k_pse(const float* __restrict__ X, float4* __restrict__ PSE)
{
    long m = (long)blockIdx.x * 256 + threadIdx.x;
    if (m >= (long)NT * NS) return;
    const float* xr = X + m * 6;
    float2 pe  = *(const float2*)xr;
    float2 t12 = *(const float2*)(xr + 2);
    float P = pe.x, E = pe.y, T1 = t12.x, T2 = t12.y;
    float den = T2 - T1;
    float ratio = (T1 + T2) / ((den == 0.f) ? 1.f : den);
    ratio = fminf(fmaxf(ratio, -1.f), 1.f);
    if ((T1 >= 0.f) || (T2 <= 0.f)) ratio = 0.f;
    float vp = 1.f - acosf(ratio) * (1.f / 3.1415f);
    if (T1 >= 0.f) vp = 1.f;
    if (T2 <= 0.f) vp = 0.f;
    PSE[m] = make_float4(P * (1.f - vp), P * vp, E, 0.f);
}

// ---------------------------------------------------------------------------
// k_mlp: fp16 MFMA GEMM [1.46M x 256] x [256 x 48], LDS-free.
//   Wave = 16 rows (flat m = t*NS+s). Lane(m=lane&15, quad=lane>>4) produces
//   its own A-frag: h[m][quad*8+j] = tanh(base + scalars . coeffs).
//   3 n-tiles: vi (W2H cols 0-15), vk (16-31), vm (32-47). Bias in acc init.
//   Epilogue: C layout col=lane&15, row=quad*4+reg -> uint2 {vi|vk u16, vm f32}.
// ---------------------------------------------------------------------------
#define LD8(dst, ptr) { float4 _a = *(const float4*)(ptr); float4 _b = *(const float4*)((ptr) + 4); \
  dst[0]=_a.x; dst[1]=_a.y; dst[2]=_a.z; dst[3]=_a.w; dst[4]=_b.x; dst[5]=_b.y; dst[6]=_b.z; dst[7]=_b.w; }

__global__ __launch_bounds__(256) void k_mlp(
    const float* __restrict__ X,
    const float* __restrict__ BASE1, const float* __restrict__ BASE2,
    const float* __restrict__ A1, const float* __restrict__ C0,
    const float* __restrict__ C1, const float* __restrict__ C2,
    const _Float16* __restrict__ W2H,
    const float* __restrict__ T1b2, const float* __restrict__ T2b2,
    uint2* __restrict__ VMK)
{
    const long MLAST = (long)NT * NS - 1;
    const int tid = threadIdx.x;
    const int wave = tid >> 6, lane = tid & 63;
    const int quad = lane >> 4, ml = lane & 15;

    long m = (long)blockIdx.x * 64 + wave * 16 + ml;
    if (m > MLAST) m = MLAST;
    const int s = (int)(m % NS);

    const float* xr = X + m * 6;
    float2 t12 = *(const float2*)(xr + 2);
    float2 rl  = *(const float2*)(xr + 4);
    const float T1v = t12.x, T2v = t12.y, Rv = rl.x, LAIv = rl.y;

    float bvi = T1b2[ml], bvk = T1b2[NH + ml], bvm = T2b2[ml];
    f32x4 acc0 = {bvi, bvi, bvi, bvi};
    f32x4 acc1 = {bvk, bvk, bvk, bvk};
    f32x4 acc2 = {bvm, bvm, bvm, bvm};

    const float* b1p = BASE1 + (size_t)s * HID + quad * 8;
    const float* b2p = BASE2 + (size_t)s * HID + quad * 8;
    const _Float16* wvi = W2H + (size_t)ml * HID;
    const _Float16* wvk = W2H + (size_t)(NH + ml) * HID;
    const _Float16* wvm = W2H + (size_t)(2 * NH + ml) * HID;

#pragma unroll 2
    for (int ks = 0; ks < 8; ++ks) {
        const int kb = ks * 32 + quad * 8;
        float b1v[8], b2v[8], a1v[8], c0v[8], c1v[8], c2v[8];
        LD8(b1v, b1p + ks * 32)
        LD8(b2v, b2p + ks * 32)
        LD8(a1v, A1 + kb)
        LD8(c0v, C0 + kb)
        LD8(c1v, C1 + kb)
        LD8(c2v, C2 + kb)

        f16x8 A1f, A2f;
#pragma unroll
        for (int j = 0; j < 8; ++j) {
            A1f[j] = (_Float16)fast_tanh(b1v[j] + LAIv * a1v[j]);
            A2f[j] = (_Float16)fast_tanh(b2v[j] + Rv * c0v[j] + T1v * c1v[j] + T2v * c2v[j]);
        }

        f16x8 Bvi = *(const f16x8*)(wvi + kb);
        f16x8 Bvk = *(const f16x8*)(wvk + kb);
        f16x8 Bvm = *(const f16x8*)(wvm + kb);

        acc0 = __builtin_amdgcn_mfma_f32_16x16x32_f16(A1f, Bvi, acc0, 0, 0, 0);
        acc1 = __builtin_amdgcn_mfma_f32_16x16x32_f16(A1f, Bvk, acc1, 0, 0, 0);
        acc2 = __builtin_amdgcn_mfma_f32_16x16x32_f16(A2f, Bvm, acc2, 0, 0, 0);
    }

    long mb = (long)blockIdx.x * 64 + wave * 16 + quad * 4;
#pragma unroll
    for (int j = 0; j < 4; ++j) {
        long mr = mb + j;
        if (mr > MLAST) mr = MLAST;
        float vi = hsigf(acc0[j]);
        float vk = hsigf(acc1[j]);
        float vm = __expf(2.f * acc2[j]);
        unsigned pk = (unsigned)(vi * 65535.f + 0.5f) | ((unsigned)(vk * 65535.f + 0.5f) << 16);
        VMK[mr * NH + ml] = make_uint2(pk, __float_as_uint(vm));
    }
}

// ---------------------------------------------------------------------------
// k_scan: 730-step bucket scan + fused causal conv (taps*ga) + h-sum.
//   One wave = 4 basins x 16 buckets; depth-8 prefetch ring on the merged
//   VMK stream (uint2 per channel-step) to cover ~900-cyc HBM latency.
// ---------------------------------------------------------------------------
__global__ __launch_bounds__(64) void k_scan(
    const uint2* __restrict__ VMK, const float4* __restrict__ PSE,
    const float* __restrict__ P8, const float* __restrict__ RKGA,
    float* __restrict__ OUT)
{
    int lane = threadIdx.x;
    int s = blockIdx.x * 4 + (lane >> 4);
    int hh = lane & 15;
    size_t ch = (size_t)s * NH + hh;

    const float4* pp = (const float4*)(P8 + (size_t)ch * 8);
    float4 pa = pp[0], pb4 = pp[1];
    float k1 = pa.x, k2 = pa.y, k23 = pa.z, k3 = pa.w;
    float gl = pb4.x, qb = pb4.y, ge1 = pb4.z, ge2 = pb4.w;

    float rk[16];
    {
        const float4* rp = (const float4*)(RKGA + (size_t)ch * 16);
#pragma unroll
        for (int i = 0; i < 4; ++i) {
            float4 v = rp[i];
            rk[4 * i] = v.x; rk[4 * i + 1] = v.y; rk[4 * i + 2] = v.z; rk[4 * i + 3] = v.w;
        }
    }

    float S0 = 0.f, Sv = 0.f, S2 = 0.f, S3 = 0.f;
    float q[14];
#pragma unroll
    for (int i = 0; i < 14; ++i) q[i] = 0.f;

    uint2 vb[8]; float4 pbf[8];
#pragma unroll
    for (int i = 0; i < 8; ++i) {
        vb[i] = VMK[(size_t)i * (NS * NH) + ch];
        pbf[i] = PSE[(size_t)i * NS + s];
    }

    int t = 0;
#define STEP(SL) { \
    uint2 v = vb[SL]; float4 ps = pbf[SL]; \
    int t2 = t + 8; if (t2 > NT - 1) t2 = NT - 1; \
    vb[SL] = VMK[(size_t)t2 * (NS * NH) + ch]; \
    pbf[SL] = PSE[(size_t)t2 * NS + s]; \
    float vi = (float)(v.x & 0xffffu) * (1.f / 65535.f); \
    float vk = (float)(v.x >> 16) * (1.f / 65535.f); \
    float vm = __uint_as_float(v.y); \
    float Ps = ps.x, Pl = ps.y, E = ps.z; \
    float H0 = S0 + Ps; \
    float qSm = fminf(H0, vm); S0 = H0 - qSm; \
    float Hv = fmaxf(Sv + Pl * (1.f - vi) - E * ge1, 0.f); \
    float qv = Sv * vk; Sv = Hv - qv; \
    float H2 = fmaxf(S2 + qSm + qv - E * ge2 + Pl * vi, 0.f); \
    float x1 = H2 - gl; \
    float Q1 = (x1 > 0.f) ? __expf(k1 * __logf(x1)) : 0.f; \
    float q2 = fminf(H2, gl) * k2; \
    float Q2 = q2 * (1.f - k23); \
    float H3 = S3 + q2 * k23; \
    float Q3 = H3 * k3 + qb; \
    S2 = H2 - Q1 - q2; S3 = H3 - Q3; \
    float qt = Q1 + Q2 + Q3; \
    float y = qt * rk[0]; \
    _Pragma("unroll") for (int d = 1; d <= 14; ++d) y += q[d - 1] * rk[d]; \
    _Pragma("unroll") for (int i = 13; i > 0; --i) q[i] = q[i - 1]; \
    q[0] = qt; \
    y += __shfl_xor(y, 1); y += __shfl_xor(y, 2); \
    y += __shfl_xor(y, 4); y += __shfl_xor(y, 8); \
    if (hh == 0) OUT[(size_t)t * NS + s] = y; \
    ++t; }

    for (int tb = 0; tb < 91; ++tb) {
        STEP(0) STEP(1) STEP(2) STEP(3) STEP(4) STEP(5) STEP(6) STEP(7)
    }
    STEP(0) STEP(1)
#undef STEP
}

// ---------------------------------------------------------------------------
extern "C" void kernel_launch(void* const* d_in, const int* in_sizes, int n_in,
                              void* d_out, int out_size, void* d_ws, size_t ws_size,
                              hipStream_t stream)
{
    const float* X    = (const float*)d_in[0];
    const float* XC   = (const float*)d_in[1];
    const float* fcW1 = (const float*)d_in[2];
    const float* fcb1 = (const float*)d_in[3];
    const float* fcW2 = (const float*)d_in[4];
    const float* fcb2 = (const float*)d_in[5];
    const float* fRW1 = (const float*)d_in[6];
    const float* fRb1 = (const float*)d_in[7];
    const float* fRW2 = (const float*)d_in[8];
    const float* fRb2 = (const float*)d_in[9];
    const float* T1W1 = (const float*)d_in[10];
    const float* T1b1 = (const float*)d_in[11];
    const float* T1W2 = (const float*)d_in[12];
    const float* T1b2 = (const float*)d_in[13];
    const float* T2W1 = (const float*)d_in[14];
    const float* T2b1 = (const float*)d_in[15];
    const float* T2W2 = (const float*)d_in[16];
    const float* T2b2 = (const float*)d_in[17];
    float* OUT = (float*)d_out;

    char* w = (char*)d_ws;
    uint2* VMK   = (uint2*)w;      w += (size_t)NT * NS * NH * 8;   // 186.9 MB
    float4* PSE  = (float4*)w;     w += (size_t)NT * NS * 16;       // 23.4 MB
    float* BASE1 = (float*)w;      w += (size_t)NS * HID * 4;
    float* BASE2 = (float*)w;      w += (size_t)NS * HID * 4;
    float* P8    = (float*)w;      w += (size_t)NS * NH * 8 * 4;
    float* RKGA  = (float*)w;      w += (size_t)NS * NH * 16 * 4;
    _Float16* W2H = (_Float16*)w;  w += 48 * HID * 2;
    float* A1    = (float*)w;      w += HID * 4;
    float* C0    = (float*)w;      w += HID * 4;
    float* C1    = (float*)w;      w += HID * 4;
    float* C2    = (float*)w;      w += HID * 4;
    (void)ws_size; (void)in_sizes; (void)n_in; (void)out_size;

    const long MTOT = (long)NT * NS;

    k_pack<<<dim3(1), dim3(256), 0, stream>>>(T1W1, T2W1, T1W2, T2W2, A1, C0, C1, C2, W2H);
    k_basin<<<dim3(NS), dim3(256), 0, stream>>>(XC, fcW1, fcb1, fcW2, fcb2,
                                                fRW1, fRb1, fRW2, fRb2,
                                                T1W1, T1b1, T2W1, T2b1,
                                                P8, RKGA, BASE1, BASE2);
    k_pse<<<dim3((unsigned)((MTOT + 255) / 256)), dim3(256), 0, stream>>>(X, PSE);
    k_mlp<<<dim3((unsigned)((MTOT + 63) / 64)), dim3(256), 0, stream>>>(
        X, BASE1, BASE2, A1, C0, C1, C2, W2H, T1b2, T2b2, VMK);
    k_scan<<<dim3(NS / 4), dim3(64), 0, stream>>>(VMK, PSE, P8, RKGA, OUT);
}

// Round 3
// 1009.608 us; speedup vs baseline: 7.9721x; 1.1687x over previous
//
#include <hip/hip_runtime.h>
#include <math.h>

#define NT 730
#define NS 2000
#define NH 16
#define NG 32
#define NR 15
#define HID 256

// 2*log2(e): pre-folded into BASE1/BASE2/A1/C0..C2 so tanh arg is a bare fma
// and tanh(x) = 1 - 2*rcp(exp2(y)+1), y = SC*x.
#define SC 2.885390081777927f

typedef _Float16 f16x8 __attribute__((ext_vector_type(8)));
typedef float f32x4 __attribute__((ext_vector_type(4)));

__device__ __forceinline__ float tanh_pre(float y) {   // y = SC * x
    float e = __builtin_amdgcn_exp2f(y);
    float r = __builtin_amdgcn_rcpf(e + 1.f);
    return fmaf(-2.f, r, 1.f);
}
__device__ __forceinline__ float fast_tanh(float x) { return tanh_pre(x * SC); }
__device__ __forceinline__ float sigmoidf_(float x) { return 1.f / (1.f + __expf(-x)); }
__device__ __forceinline__ float hsigf(float x) { return fminf(fmaxf(x * (1.f / 6.f) + 0.5f, 0.f), 1.f); }

#define LD8(dst, ptr) { float4 _a = *(const float4*)(ptr); float4 _b = *(const float4*)((ptr) + 4); \
  dst[0]=_a.x; dst[1]=_a.y; dst[2]=_a.z; dst[3]=_a.w; dst[4]=_b.x; dst[5]=_b.y; dst[6]=_b.z; dst[7]=_b.w; }

// ---------------------------------------------------------------------------
// k_pack: gather small weight slices; coefficient columns pre-scaled by SC.
// ---------------------------------------------------------------------------
__global__ __launch_bounds__(256) void k_pack(
    const float* __restrict__ T1W1, const float* __restrict__ T2W1,
    const float* __restrict__ T1W2, const float* __restrict__ T2W2,
    float* __restrict__ A1, float* __restrict__ C0, float* __restrict__ C1,
    float* __restrict__ C2, _Float16* __restrict__ W2H)
{
    int k = threadIdx.x;
    A1[k] = SC * T1W1[k * (1 + NG)];
    C0[k] = SC * T2W1[k * (3 + NG)];
    C1[k] = SC * T2W1[k * (3 + NG) + 1];
    C2[k] = SC * T2W1[k * (3 + NG) + 2];
    for (int c = 0; c < 48; ++c)
        W2H[c * HID + k] = (_Float16)((c < 32) ? T1W2[c * HID + k] : T2W2[(c - 32) * HID + k]);
}

// ---------------------------------------------------------------------------
// k_basin: per-basin MLPs + derived params. BASE1/BASE2 stored pre-scaled by SC.
// ---------------------------------------------------------------------------
__global__ __launch_bounds__(256) void k_basin(
    const float* __restrict__ XC,
    const float* __restrict__ fcW1, const float* __restrict__ fcb1,
    const float* __restrict__ fcW2, const float* __restrict__ fcb2,
    const float* __restrict__ fRW1, const float* __restrict__ fRb1,
    const float* __restrict__ fRW2, const float* __restrict__ fRb2,
    const float* __restrict__ T1W1, const float* __restrict__ T1b1,
    const float* __restrict__ T2W1, const float* __restrict__ T2b1,
    float* __restrict__ P8, float* __restrict__ RKGA,
    float* __restrict__ BASE1, float* __restrict__ BASE2)
{
    int s = blockIdx.x, tid = threadIdx.x;
    __shared__ float xcs[NG];
    __shared__ float h[HID], hR[HID];
    __shared__ float wbuf[10 * NH], wRbuf[NH * NR];
    __shared__ float gav[NH];

    if (tid < NG) xcs[tid] = XC[s * NG + tid];
    __syncthreads();

    {
        float a = fcb1[tid], aR = fRb1[tid];
        const float4* w4  = (const float4*)(fcW1 + tid * NG);
        const float4* wR4 = (const float4*)(fRW1 + tid * NG);
        const float4* x4  = (const float4*)xcs;
#pragma unroll
        for (int g = 0; g < NG / 4; ++g) {
            float4 xv = x4[g], wv = w4[g], rv = wR4[g];
            a  += xv.x * wv.x + xv.y * wv.y + xv.z * wv.z + xv.w * wv.w;
            aR += xv.x * rv.x + xv.y * rv.y + xv.z * rv.z + xv.w * rv.w;
        }
        h[tid] = fast_tanh(a);
        hR[tid] = fast_tanh(aR);
    }
    {
        float b1 = T1b1[tid], b2 = T2b1[tid];
        const float* w1 = T1W1 + tid * (1 + NG) + 1;
        const float* w2 = T2W1 + tid * (3 + NG) + 3;
#pragma unroll 8
        for (int g = 0; g < NG; ++g) { float xv = xcs[g]; b1 += xv * w1[g]; b2 += xv * w2[g]; }
        BASE1[(size_t)s * HID + tid] = SC * b1;
        BASE2[(size_t)s * HID + tid] = SC * b2;
    }
    __syncthreads();

    if (tid < 10 * NH) {
        float a = fcb2[tid];
        const float4* w4 = (const float4*)(fcW2 + tid * HID);
        const float4* h4 = (const float4*)h;
        for (int k = 0; k < HID / 4; ++k) {
            float4 hv = h4[k], wv = w4[k];
            a += hv.x * wv.x + hv.y * wv.y + hv.z * wv.z + hv.w * wv.w;
        }
        wbuf[tid] = a;
    }
    if (tid < NH * NR) {
        float a = fRb2[tid];
        const float4* w4 = (const float4*)(fRW2 + tid * HID);
        const float4* h4 = (const float4*)hR;
        for (int k = 0; k < HID / 4; ++k) {
            float4 hv = h4[k], wv = w4[k];
            a += hv.x * wv.x + hv.y * wv.y + hv.z * wv.z + hv.w * wv.w;
        }
        wRbuf[tid] = a;
    }
    __syncthreads();

    if (tid < NH) {
        int hh = tid;
        float mx = -1e30f;
        for (int i = 0; i < NH; ++i) mx = fmaxf(mx, wbuf[6 * NH + i]);
        float sum = 0.f;
        for (int i = 0; i < NH; ++i) sum += expf(wbuf[6 * NH + i] - mx);
        gav[hh] = expf(wbuf[6 * NH + hh] - mx) / sum;

        float* p = P8 + (size_t)(s * NH + hh) * 8;
        p[0] = sigmoidf_(wbuf[1 * NH + hh]);
        p[1] = sigmoidf_(wbuf[2 * NH + hh]);
        p[2] = sigmoidf_(wbuf[3 * NH + hh]);
        p[3] = sigmoidf_(wbuf[4 * NH + hh]) * 0.1f;
        p[4] = expf(wbuf[5 * NH + hh]) * 2.f;
        p[5] = fmaxf(wbuf[7 * NH + hh], 0.f);
        p[6] = fmaxf(wbuf[8 * NH + hh], 0.f);
        p[7] = fmaxf(wbuf[9 * NH + hh], 0.f);
    }
    __syncthreads();

    if (tid < NH * NR) {
        int hh = tid / NR, j = tid % NR;
        RKGA[(size_t)(s * NH + hh) * 16 + (NR - 1 - j)] = gav[hh] * fmaxf(wRbuf[hh * NR + j], 0.f);
    }
}

// ---------------------------------------------------------------------------
// PSE epilogue helper (vp partition) — one lane per row.
// ---------------------------------------------------------------------------
__device__ __forceinline__ void store_pse(float4* __restrict__ PSE, long m, float2 pe, float2 t12) {
    float P = pe.x, E = pe.y, T1 = t12.x, T2 = t12.y;
    float den = T2 - T1;
    float ratio = (T1 + T2) / ((den == 0.f) ? 1.f : den);
    ratio = fminf(fmaxf(ratio, -1.f), 1.f);
    if ((T1 >= 0.f) || (T2 <= 0.f)) ratio = 0.f;
    float vp = 1.f - acosf(ratio) * (1.f / 3.1415f);
    if (T1 >= 0.f) vp = 1.f;
    if (T2 <= 0.f) vp = 0.f;
    PSE[m] = make_float4(P * (1.f - vp), P * vp, E, 0.f);
}

// ---------------------------------------------------------------------------
// k_mlp: fp16 MFMA GEMM [1.46M x 256] x [256 x 48], LDS-free, M2-tiled.
//   Wave = 2 tiles x 16 rows. Lane(m=lane&15, quad=lane>>4) builds its own
//   A-frags (tanh via exp2+rcp, args pre-scaled by SC). Coefficient and
//   B-fragment loads amortized over both tiles. PSE fused into epilogue.
// ---------------------------------------------------------------------------
__global__ __launch_bounds__(256) void k_mlp(
    const float* __restrict__ X,
    const float* __restrict__ BASE1, const float* __restrict__ BASE2,
    const float* __restrict__ A1, const float* __restrict__ C0,
    const float* __restrict__ C1, const float* __restrict__ C2,
    const _Float16* __restrict__ W2H,
    const float* __restrict__ T1b2, const float* __restrict__ T2b2,
    uint2* __restrict__ VMK, float4* __restrict__ PSE)
{
    const long MLAST = (long)NT * NS - 1;
    const int tid = threadIdx.x;
    const int wave = tid >> 6, lane = tid & 63;
    const int quad = lane >> 4, ml = lane & 15;
    const long wbase = (long)blockIdx.x * 128 + (long)wave * 32;

    long m0 = wbase + ml;       if (m0 > MLAST) m0 = MLAST;
    long m1 = wbase + 16 + ml;  if (m1 > MLAST) m1 = MLAST;
    const int s0 = (int)(m0 % NS), s1 = (int)(m1 % NS);

    const float* xr0 = X + m0 * 6;
    const float* xr1 = X + m1 * 6;
    float2 pe0 = *(const float2*)(xr0);
    float2 t0  = *(const float2*)(xr0 + 2);
    float2 rl0 = *(const float2*)(xr0 + 4);
    float2 pe1 = *(const float2*)(xr1);
    float2 t1  = *(const float2*)(xr1 + 2);
    float2 rl1 = *(const float2*)(xr1 + 4);

    float bvi = T1b2[ml], bvk = T1b2[NH + ml], bvm = T2b2[ml];
    f32x4 ac0[2], ac1[2], ac2[2];
#pragma unroll
    for (int i = 0; i < 2; ++i) {
        ac0[i] = (f32x4){bvi, bvi, bvi, bvi};
        ac1[i] = (f32x4){bvk, bvk, bvk, bvk};
        ac2[i] = (f32x4){bvm, bvm, bvm, bvm};
    }

    const float* b1q0 = BASE1 + (size_t)s0 * HID + quad * 8;
    const float* b2q0 = BASE2 + (size_t)s0 * HID + quad * 8;
    const float* b1q1 = BASE1 + (size_t)s1 * HID + quad * 8;
    const float* b2q1 = BASE2 + (size_t)s1 * HID + quad * 8;
    const _Float16* wvi = W2H + (size_t)ml * HID;
    const _Float16* wvk = W2H + (size_t)(NH + ml) * HID;
    const _Float16* wvm = W2H + (size_t)(2 * NH + ml) * HID;

#pragma unroll 2
    for (int ks = 0; ks < 8; ++ks) {
        const int kb = ks * 32 + quad * 8;
        float a1v[8], c0v[8], c1v[8], c2v[8];
        LD8(a1v, A1 + kb)
        LD8(c0v, C0 + kb)
        LD8(c1v, C1 + kb)
        LD8(c2v, C2 + kb)
        f16x8 Bvi = *(const f16x8*)(wvi + kb);
        f16x8 Bvk = *(const f16x8*)(wvk + kb);
        f16x8 Bvm = *(const f16x8*)(wvm + kb);

#define TILE(BP1, BP2, RLV, TV, IDX) { \
        float b1v[8], b2v[8]; \
        LD8(b1v, BP1 + ks * 32) \
        LD8(b2v, BP2 + ks * 32) \
        f16x8 Af1, Af2; \
        _Pragma("unroll") \
        for (int j = 0; j < 8; ++j) { \
            Af1[j] = (_Float16)tanh_pre(fmaf(RLV.y, a1v[j], b1v[j])); \
            float y2 = fmaf(RLV.x, c0v[j], b2v[j]); \
            y2 = fmaf(TV.x, c1v[j], y2); \
            y2 = fmaf(TV.y, c2v[j], y2); \
            Af2[j] = (_Float16)tanh_pre(y2); \
        } \
        ac0[IDX] = __builtin_amdgcn_mfma_f32_16x16x32_f16(Af1, Bvi, ac0[IDX], 0, 0, 0); \
        ac1[IDX] = __builtin_amdgcn_mfma_f32_16x16x32_f16(Af1, Bvk, ac1[IDX], 0, 0, 0); \
        ac2[IDX] = __builtin_amdgcn_mfma_f32_16x16x32_f16(Af2, Bvm, ac2[IDX], 0, 0, 0); }

        TILE(b1q0, b2q0, rl0, t0, 0)
        TILE(b1q1, b2q1, rl1, t1, 1)
#undef TILE
    }

#pragma unroll
    for (int tile = 0; tile < 2; ++tile) {
        long mb = wbase + tile * 16 + quad * 4;
#pragma unroll
        for (int j = 0; j < 4; ++j) {
            long mr = mb + j;
            if (mr > MLAST) mr = MLAST;
            float vi = hsigf(ac0[tile][j]);
            float vk = hsigf(ac1[tile][j]);
            float vm = __expf(2.f * ac2[tile][j]);
            unsigned pk = (unsigned)(vi * 65535.f + 0.5f) | ((unsigned)(vk * 65535.f + 0.5f) << 16);
            VMK[mr * NH + ml] = make_uint2(pk, __float_as_uint(vm));
        }
    }
    if (quad == 0) {
        store_pse(PSE, m0, pe0, t0);
        store_pse(PSE, m1, pe1, t1);
    }
}

// ---------------------------------------------------------------------------
// k_scan: 730-step bucket scan + fused causal conv (taps*ga) + h-sum.
//   One wave = 4 basins x 16 buckets; depth-10 prefetch ring (730 = 73*10).
// ---------------------------------------------------------------------------
__global__ __launch_bounds__(64) void k_scan(
    const uint2* __restrict__ VMK, const float4* __restrict__ PSE,
    const float* __restrict__ P8, const float* __restrict__ RKGA,
    float* __restrict__ OUT)
{
    int lane = threadIdx.x;
    int s = blockIdx.x * 4 + (lane >> 4);
    int hh = lane & 15;
    size_t ch = (size_t)s * NH + hh;

    const float4* pp = (const float4*)(P8 + (size_t)ch * 8);
    float4 pa = pp[0], pb4 = pp[1];
    float k1 = pa.x, k2 = pa.y, k23 = pa.z, k3 = pa.w;
    float gl = pb4.x, qb = pb4.y, ge1 = pb4.z, ge2 = pb4.w;

    float rk[16];
    {
        const float4* rp = (const float4*)(RKGA + (size_t)ch * 16);
#pragma unroll
        for (int i = 0; i < 4; ++i) {
            float4 v = rp[i];
            rk[4 * i] = v.x; rk[4 * i + 1] = v.y; rk[4 * i + 2] = v.z; rk[4 * i + 3] = v.w;
        }
    }

    float S0 = 0.f, Sv = 0.f, S2 = 0.f, S3 = 0.f;
    float q[14];
#pragma unroll
    for (int i = 0; i < 14; ++i) q[i] = 0.f;

    uint2 vb[10]; float4 pbf[10];
#pragma unroll
    for (int i = 0; i < 10; ++i) {
        vb[i] = VMK[(size_t)i * (NS * NH) + ch];
        pbf[i] = PSE[(size_t)i * NS + s];
    }

    int t = 0;
#define STEP(SL) { \
    uint2 v = vb[SL]; float4 ps = pbf[SL]; \
    int t2 = t + 10; if (t2 > NT - 1) t2 = NT - 1; \
    vb[SL] = VMK[(size_t)t2 * (NS * NH) + ch]; \
    pbf[SL] = PSE[(size_t)t2 * NS + s]; \
    float vi = (float)(v.x & 0xffffu) * (1.f / 65535.f); \
    float vk = (float)(v.x >> 16) * (1.f / 65535.f); \
    float vm = __uint_as_float(v.y); \
    float Ps = ps.x, Pl = ps.y, E = ps.z; \
    float H0 = S0 + Ps; \
    float qSm = fminf(H0, vm); S0 = H0 - qSm; \
    float Hv = fmaxf(Sv + Pl * (1.f - vi) - E * ge1, 0.f); \
    float qv = Sv * vk; Sv = Hv - qv; \
    float H2 = fmaxf(S2 + qSm + qv - E * ge2 + Pl * vi, 0.f); \
    float x1 = H2 - gl; \
    float Q1 = (x1 > 0.f) ? __expf(k1 * __logf(x1)) : 0.f; \
    float q2 = fminf(H2, gl) * k2; \
    float Q2 = q2 * (1.f - k23); \
    float H3 = S3 + q2 * k23; \
    float Q3 = H3 * k3 + qb; \
    S2 = H2 - Q1 - q2; S3 = H3 - Q3; \
    float qt = Q1 + Q2 + Q3; \
    float y = qt * rk[0]; \
    _Pragma("unroll") for (int d = 1; d <= 14; ++d) y += q[d - 1] * rk[d]; \
    _Pragma("unroll") for (int i = 13; i > 0; --i) q[i] = q[i - 1]; \
    q[0] = qt; \
    y += __shfl_xor(y, 1); y += __shfl_xor(y, 2); \
    y += __shfl_xor(y, 4); y += __shfl_xor(y, 8); \
    if (hh == 0) OUT[(size_t)t * NS + s] = y; \
    ++t; }

    for (int tb = 0; tb < 73; ++tb) {
        STEP(0) STEP(1) STEP(2) STEP(3) STEP(4)
        STEP(5) STEP(6) STEP(7) STEP(8) STEP(9)
    }
#undef STEP
}

// ---------------------------------------------------------------------------
extern "C" void kernel_launch(void* const* d_in, const int* in_sizes, int n_in,
                              void* d_out, int out_size, void* d_ws, size_t ws_size,
                              hipStream_t stream)
{
    const float* X    = (const float*)d_in[0];
    const float* XC   = (const float*)d_in[1];
    const float* fcW1 = (const float*)d_in[2];
    const float* fcb1 = (const float*)d_in[3];
    const float* fcW2 = (const float*)d_in[4];
    const float* fcb2 = (const float*)d_in[5];
    const float* fRW1 = (const float*)d_in[6];
    const float* fRb1 = (const float*)d_in[7];
    const float* fRW2 = (const float*)d_in[8];
    const float* fRb2 = (const float*)d_in[9];
    const float* T1W1 = (const float*)d_in[10];
    const float* T1b1 = (const float*)d_in[11];
    const float* T1W2 = (const float*)d_in[12];
    const float* T1b2 = (const float*)d_in[13];
    const float* T2W1 = (const float*)d_in[14];
    const float* T2b1 = (const float*)d_in[15];
    const float* T2W2 = (const float*)d_in[16];
    const float* T2b2 = (const float*)d_in[17];
    float* OUT = (float*)d_out;

    char* w = (char*)d_ws;
    uint2* VMK   = (uint2*)w;      w += (size_t)NT * NS * NH * 8;   // 186.9 MB
    float4* PSE  = (float4*)w;     w += (size_t)NT * NS * 16;       // 23.4 MB
    float* BASE1 = (float*)w;      w += (size_t)NS * HID * 4;
    float* BASE2 = (float*)w;      w += (size_t)NS * HID * 4;
    float* P8    = (float*)w;      w += (size_t)NS * NH * 8 * 4;
    float* RKGA  = (float*)w;      w += (size_t)NS * NH * 16 * 4;
    _Float16* W2H = (_Float16*)w;  w += 48 * HID * 2;
    float* A1    = (float*)w;      w += HID * 4;
    float* C0    = (float*)w;      w += HID * 4;
    float* C1    = (float*)w;      w += HID * 4;
    float* C2    = (float*)w;      w += HID * 4;
    (void)ws_size; (void)in_sizes; (void)n_in; (void)out_size;

    const long MTOT = (long)NT * NS;

    k_pack<<<dim3(1), dim3(256), 0, stream>>>(T1W1, T2W1, T1W2, T2W2, A1, C0, C1, C2, W2H);
    k_basin<<<dim3(NS), dim3(256), 0, stream>>>(XC, fcW1, fcb1, fcW2, fcb2,
                                                fRW1, fRb1, fRW2, fRb2,
                                                T1W1, T1b1, T2W1, T2b1,
                                                P8, RKGA, BASE1, BASE2);
    k_mlp<<<dim3((unsigned)((MTOT + 127) / 128)), dim3(256), 0, stream>>>(
        X, BASE1, BASE2, A1, C0, C1, C2, W2H, T1b2, T2b2, VMK, PSE);
    k_scan<<<dim3(NS / 4), dim3(64), 0, stream>>>(VMK, PSE, P8, RKGA, OUT);
}

// Round 4
// 702.168 us; speedup vs baseline: 11.4627x; 1.4378x over previous
//
#include <hip/hip_runtime.h>
#include <math.h>

#define NT 730
#define NS 2000
#define NH 16
#define NG 32
#define NR 15
#define HID 256

// 2*log2(e): pre-folded into BASE1/BASE2/A1/C0..C2 so tanh arg is a bare fma
// and tanh(x) = 1 - 2*rcp(exp2(y)+1), y = SC*x.
#define SC 2.885390081777927f

typedef _Float16 f16x8 __attribute__((ext_vector_type(8)));
typedef float f32x4 __attribute__((ext_vector_type(4)));

__device__ __forceinline__ float tanh_pre(float y) {   // y = SC * x
    float e = __builtin_amdgcn_exp2f(y);
    float r = __builtin_amdgcn_rcpf(e + 1.f);
    return fmaf(-2.f, r, 1.f);
}
__device__ __forceinline__ float fast_tanh(float x) { return tanh_pre(x * SC); }
__device__ __forceinline__ float sigmoidf_(float x) { return 1.f / (1.f + __expf(-x)); }
__device__ __forceinline__ float hsigf(float x) { return fminf(fmaxf(x * (1.f / 6.f) + 0.5f, 0.f), 1.f); }

#define LD8(dst, ptr) { float4 _a = *(const float4*)(ptr); float4 _b = *(const float4*)((ptr) + 4); \
  dst[0]=_a.x; dst[1]=_a.y; dst[2]=_a.z; dst[3]=_a.w; dst[4]=_b.x; dst[5]=_b.y; dst[6]=_b.z; dst[7]=_b.w; }

// ---------------------------------------------------------------------------
// k_pack: gather small weight slices; coefficient columns pre-scaled by SC.
// ---------------------------------------------------------------------------
__global__ __launch_bounds__(256) void k_pack(
    const float* __restrict__ T1W1, const float* __restrict__ T2W1,
    const float* __restrict__ T1W2, const float* __restrict__ T2W2,
    float* __restrict__ A1, float* __restrict__ C0, float* __restrict__ C1,
    float* __restrict__ C2, _Float16* __restrict__ W2H)
{
    int k = threadIdx.x;
    A1[k] = SC * T1W1[k * (1 + NG)];
    C0[k] = SC * T2W1[k * (3 + NG)];
    C1[k] = SC * T2W1[k * (3 + NG) + 1];
    C2[k] = SC * T2W1[k * (3 + NG) + 2];
    for (int c = 0; c < 48; ++c)
        W2H[c * HID + k] = (_Float16)((c < 32) ? T1W2[c * HID + k] : T2W2[(c - 32) * HID + k]);
}

// ---------------------------------------------------------------------------
// k_basin: per-basin MLPs + derived params. BASE1/BASE2 stored pre-scaled by SC.
// ---------------------------------------------------------------------------
__global__ __launch_bounds__(256) void k_basin(
    const float* __restrict__ XC,
    const float* __restrict__ fcW1, const float* __restrict__ fcb1,
    const float* __restrict__ fcW2, const float* __restrict__ fcb2,
    const float* __restrict__ fRW1, const float* __restrict__ fRb1,
    const float* __restrict__ fRW2, const float* __restrict__ fRb2,
    const float* __restrict__ T1W1, const float* __restrict__ T1b1,
    const float* __restrict__ T2W1, const float* __restrict__ T2b1,
    float* __restrict__ P8, float* __restrict__ RKGA,
    float* __restrict__ BASE1, float* __restrict__ BASE2)
{
    int s = blockIdx.x, tid = threadIdx.x;
    __shared__ float xcs[NG];
    __shared__ float h[HID], hR[HID];
    __shared__ float wbuf[10 * NH], wRbuf[NH * NR];
    __shared__ float gav[NH];

    if (tid < NG) xcs[tid] = XC[s * NG + tid];
    __syncthreads();

    {
        float a = fcb1[tid], aR = fRb1[tid];
        const float4* w4  = (const float4*)(fcW1 + tid * NG);
        const float4* wR4 = (const float4*)(fRW1 + tid * NG);
        const float4* x4  = (const float4*)xcs;
#pragma unroll
        for (int g = 0; g < NG / 4; ++g) {
            float4 xv = x4[g], wv = w4[g], rv = wR4[g];
            a  += xv.x * wv.x + xv.y * wv.y + xv.z * wv.z + xv.w * wv.w;
            aR += xv.x * rv.x + xv.y * rv.y + xv.z * rv.z + xv.w * rv.w;
        }
        h[tid] = fast_tanh(a);
        hR[tid] = fast_tanh(aR);
    }
    {
        float b1 = T1b1[tid], b2 = T2b1[tid];
        const float* w1 = T1W1 + tid * (1 + NG) + 1;
        const float* w2 = T2W1 + tid * (3 + NG) + 3;
#pragma unroll 8
        for (int g = 0; g < NG; ++g) { float xv = xcs[g]; b1 += xv * w1[g]; b2 += xv * w2[g]; }
        BASE1[(size_t)s * HID + tid] = SC * b1;
        BASE2[(size_t)s * HID + tid] = SC * b2;
    }
    __syncthreads();

    if (tid < 10 * NH) {
        float a = fcb2[tid];
        const float4* w4 = (const float4*)(fcW2 + tid * HID);
        const float4* h4 = (const float4*)h;
        for (int k = 0; k < HID / 4; ++k) {
            float4 hv = h4[k], wv = w4[k];
            a += hv.x * wv.x + hv.y * wv.y + hv.z * wv.z + hv.w * wv.w;
        }
        wbuf[tid] = a;
    }
    if (tid < NH * NR) {
        float a = fRb2[tid];
        const float4* w4 = (const float4*)(fRW2 + tid * HID);
        const float4* h4 = (const float4*)hR;
        for (int k = 0; k < HID / 4; ++k) {
            float4 hv = h4[k], wv = w4[k];
            a += hv.x * wv.x + hv.y * wv.y + hv.z * wv.z + hv.w * wv.w;
        }
        wRbuf[tid] = a;
    }
    __syncthreads();

    if (tid < NH) {
        int hh = tid;
        float mx = -1e30f;
        for (int i = 0; i < NH; ++i) mx = fmaxf(mx, wbuf[6 * NH + i]);
        float sum = 0.f;
        for (int i = 0; i < NH; ++i) sum += expf(wbuf[6 * NH + i] - mx);
        gav[hh] = expf(wbuf[6 * NH + hh] - mx) / sum;

        float* p = P8 + (size_t)(s * NH + hh) * 8;
        p[0] = sigmoidf_(wbuf[1 * NH + hh]);
        p[1] = sigmoidf_(wbuf[2 * NH + hh]);
        p[2] = sigmoidf_(wbuf[3 * NH + hh]);
        p[3] = sigmoidf_(wbuf[4 * NH + hh]) * 0.1f;
        p[4] = expf(wbuf[5 * NH + hh]) * 2.f;
        p[5] = fmaxf(wbuf[7 * NH + hh], 0.f);
        p[6] = fmaxf(wbuf[8 * NH + hh], 0.f);
        p[7] = fmaxf(wbuf[9 * NH + hh], 0.f);
    }
    __syncthreads();

    if (tid < NH * NR) {
        int hh = tid / NR, j = tid % NR;
        RKGA[(size_t)(s * NH + hh) * 16 + (NR - 1 - j)] = gav[hh] * fmaxf(wRbuf[hh * NR + j], 0.f);
    }
}

// ---------------------------------------------------------------------------
// PSE helper (vp partition).
// ---------------------------------------------------------------------------
__device__ __forceinline__ void store_pse(float4* __restrict__ PSE, long m, float2 pe, float2 t12) {
    float P = pe.x, E = pe.y, T1 = t12.x, T2 = t12.y;
    float den = T2 - T1;
    float ratio = (T1 + T2) / ((den == 0.f) ? 1.f : den);
    ratio = fminf(fmaxf(ratio, -1.f), 1.f);
    if ((T1 >= 0.f) || (T2 <= 0.f)) ratio = 0.f;
    float vp = 1.f - acosf(ratio) * (1.f / 3.1415f);
    if (T1 >= 0.f) vp = 1.f;
    if (T2 <= 0.f) vp = 0.f;
    PSE[m] = make_float4(P * (1.f - vp), P * vp, E, 0.f);
}

// ---------------------------------------------------------------------------
// k_mlp v4: t-reuse tiling. Wave pins one 16-s tile, sweeps 4 time-tiles.
//   BASE1/BASE2/coeff/B-fragment loads are s,k-dependent only -> issued once
//   per ks-step and amortized over 4 tiles (12 MFMAs). Lane(quad,ml) builds
//   A[m=ml][k=quad*8+j] from its OWN row's scalars (held in regs for 4 t).
//   Grid: x = s-tile (125), y = t-chunk of 16 (46); block = 4 waves, wave w
//   covers t0 = gy*16+w*4 .. +3 (clamped; duplicate tail stores are identical).
// ---------------------------------------------------------------------------
__global__ __launch_bounds__(256) void k_mlp(
    const float* __restrict__ X,
    const float* __restrict__ BASE1, const float* __restrict__ BASE2,
    const float* __restrict__ A1, const float* __restrict__ C0,
    const float* __restrict__ C1, const float* __restrict__ C2,
    const _Float16* __restrict__ W2H,
    const float* __restrict__ T1b2, const float* __restrict__ T2b2,
    uint2* __restrict__ VMK, float4* __restrict__ PSE)
{
    const int tid = threadIdx.x;
    const int wave = tid >> 6, lane = tid & 63;
    const int quad = lane >> 4, ml = lane & 15;
    const int s0 = blockIdx.x * 16;
    const int t0 = blockIdx.y * 16 + wave * 4;
    const int srow = s0 + ml;

    int tcl[4];
#pragma unroll
    for (int j = 0; j < 4; ++j) { int tt = t0 + j; tcl[j] = (tt < NT) ? tt : (NT - 1); }

    float2 t12[4], rl[4];
#pragma unroll
    for (int j = 0; j < 4; ++j) {
        const float* xr = X + ((long)tcl[j] * NS + srow) * 6;
        t12[j] = *(const float2*)(xr + 2);
        rl[j]  = *(const float2*)(xr + 4);
    }
    float2 pe = *(const float2*)(X + ((long)tcl[quad] * NS + srow) * 6);

    const float bvi = T1b2[ml], bvk = T1b2[NH + ml], bvm = T2b2[ml];
    f32x4 ac0[4], ac1[4], ac2[4];
#pragma unroll
    for (int j = 0; j < 4; ++j) {
        ac0[j] = (f32x4){bvi, bvi, bvi, bvi};
        ac1[j] = (f32x4){bvk, bvk, bvk, bvk};
        ac2[j] = (f32x4){bvm, bvm, bvm, bvm};
    }

    const float* b1p = BASE1 + (size_t)srow * HID;
    const float* b2p = BASE2 + (size_t)srow * HID;
    const _Float16* wvi = W2H + (size_t)ml * HID;
    const _Float16* wvk = W2H + (size_t)(NH + ml) * HID;
    const _Float16* wvm = W2H + (size_t)(2 * NH + ml) * HID;

#pragma unroll 2
    for (int ks = 0; ks < 8; ++ks) {
        const int kb = ks * 32 + quad * 8;
        float a1v[8], c0v[8], c1v[8], c2v[8], b1v[8], b2v[8];
        LD8(a1v, A1 + kb)
        LD8(c0v, C0 + kb)
        LD8(c1v, C1 + kb)
        LD8(c2v, C2 + kb)
        LD8(b1v, b1p + kb)
        LD8(b2v, b2p + kb)
        f16x8 Bvi = *(const f16x8*)(wvi + kb);
        f16x8 Bvk = *(const f16x8*)(wvk + kb);
        f16x8 Bvm = *(const f16x8*)(wvm + kb);

#pragma unroll
        for (int j = 0; j < 4; ++j) {
            f16x8 Af1, Af2;
#pragma unroll
            for (int i = 0; i < 8; ++i) {
                Af1[i] = (_Float16)tanh_pre(fmaf(rl[j].y, a1v[i], b1v[i]));
                float y2 = fmaf(rl[j].x, c0v[i], b2v[i]);
                y2 = fmaf(t12[j].x, c1v[i], y2);
                y2 = fmaf(t12[j].y, c2v[i], y2);
                Af2[i] = (_Float16)tanh_pre(y2);
            }
            ac0[j] = __builtin_amdgcn_mfma_f32_16x16x32_f16(Af1, Bvi, ac0[j], 0, 0, 0);
            ac1[j] = __builtin_amdgcn_mfma_f32_16x16x32_f16(Af1, Bvk, ac1[j], 0, 0, 0);
            ac2[j] = __builtin_amdgcn_mfma_f32_16x16x32_f16(Af2, Bvm, ac2[j], 0, 0, 0);
        }
    }

    // Epilogue: C layout col(ml)=output ch, row = quad*4+reg = s-offset in tile.
#pragma unroll
    for (int j = 0; j < 4; ++j) {
        long rowbase = (long)tcl[j] * NS + s0 + quad * 4;
#pragma unroll
        for (int rg = 0; rg < 4; ++rg) {
            float vi = hsigf(ac0[j][rg]);
            float vk = hsigf(ac1[j][rg]);
            float vm = __expf(2.f * ac2[j][rg]);
            unsigned pk = (unsigned)(vi * 65535.f + 0.5f) | ((unsigned)(vk * 65535.f + 0.5f) << 16);
            VMK[(rowbase + rg) * NH + ml] = make_uint2(pk, __float_as_uint(vm));
        }
    }
    store_pse(PSE, (long)tcl[quad] * NS + srow, pe, t12[quad]);
}

// ---------------------------------------------------------------------------
// k_scan v2: 730-step bucket scan + fused causal conv (taps*ga) + h-sum.
//   One wave = 4 basins x 16 buckets. Mod-14 sample ring (no shift movs) with
//   prefetch depth 14 = ring period; fully unrolled so all indices are const.
// ---------------------------------------------------------------------------
__global__ __launch_bounds__(64) void k_scan(
    const uint2* __restrict__ VMK, const float4* __restrict__ PSE,
    const float* __restrict__ P8, const float* __restrict__ RKGA,
    float* __restrict__ OUT)
{
    int lane = threadIdx.x;
    int s = blockIdx.x * 4 + (lane >> 4);
    int hh = lane & 15;
    size_t ch = (size_t)s * NH + hh;

    const float4* pp = (const float4*)(P8 + (size_t)ch * 8);
    float4 pa = pp[0], pb4 = pp[1];
    float k1 = pa.x, k2 = pa.y, k23 = pa.z, k3 = pa.w;
    float gl = pb4.x, qb = pb4.y, ge1 = pb4.z, ge2 = pb4.w;

    float rk[16];
    {
        const float4* rp = (const float4*)(RKGA + (size_t)ch * 16);
#pragma unroll
        for (int i = 0; i < 4; ++i) {
            float4 v = rp[i];
            rk[4 * i] = v.x; rk[4 * i + 1] = v.y; rk[4 * i + 2] = v.z; rk[4 * i + 3] = v.w;
        }
    }

    float S0 = 0.f, Sv = 0.f, S2 = 0.f, S3 = 0.f;
    float qr[14];
#pragma unroll
    for (int i = 0; i < 14; ++i) qr[i] = 0.f;

    uint2 vb[14]; float4 pbf[14];
#pragma unroll
    for (int i = 0; i < 14; ++i) {
        vb[i] = VMK[(size_t)i * (NS * NH) + ch];
        pbf[i] = PSE[(size_t)i * NS + s];
    }

    int t = 0;
#define SBODY(I) { \
    uint2 v = vb[I]; float4 ps = pbf[I]; \
    int t2 = t + 14; if (t2 > NT - 1) t2 = NT - 1; \
    vb[I] = VMK[(size_t)t2 * (NS * NH) + ch]; \
    pbf[I] = PSE[(size_t)t2 * NS + s]; \
    float vi = (float)(v.x & 0xffffu) * (1.f / 65535.f); \
    float vk = (float)(v.x >> 16) * (1.f / 65535.f); \
    float vm = __uint_as_float(v.y); \
    float Ps = ps.x, Pl = ps.y, E = ps.z; \
    float H0 = S0 + Ps; \
    float qSm = fminf(H0, vm); S0 = H0 - qSm; \
    float Hv = fmaxf(Sv + Pl * (1.f - vi) - E * ge1, 0.f); \
    float qv = Sv * vk; Sv = Hv - qv; \
    float H2 = fmaxf(S2 + qSm + qv - E * ge2 + Pl * vi, 0.f); \
    float x1 = H2 - gl; \
    float Q1 = (x1 > 0.f) ? __expf(k1 * __logf(x1)) : 0.f; \
    float q2 = fminf(H2, gl) * k2; \
    float Q2 = q2 * (1.f - k23); \
    float H3 = S3 + q2 * k23; \
    float Q3 = H3 * k3 + qb; \
    S2 = H2 - Q1 - q2; S3 = H3 - Q3; \
    float qt = Q1 + Q2 + Q3; \
    float y = qt * rk[0]; \
    _Pragma("unroll") for (int d = 1; d <= 14; ++d) y += qr[((I) + 14 - d) % 14] * rk[d]; \
    qr[I] = qt; \
    y += __shfl_xor(y, 1); y += __shfl_xor(y, 2); \
    y += __shfl_xor(y, 4); y += __shfl_xor(y, 8); \
    if (hh == 0) OUT[(size_t)t * NS + s] = y; \
    ++t; }

    for (int tb = 0; tb < 52; ++tb) {          // 52 * 14 = 728 steps
        SBODY(0) SBODY(1) SBODY(2) SBODY(3) SBODY(4) SBODY(5) SBODY(6)
        SBODY(7) SBODY(8) SBODY(9) SBODY(10) SBODY(11) SBODY(12) SBODY(13)
    }
    SBODY(0) SBODY(1)                          // steps 728, 729
#undef SBODY
}

// ---------------------------------------------------------------------------
extern "C" void kernel_launch(void* const* d_in, const int* in_sizes, int n_in,
                              void* d_out, int out_size, void* d_ws, size_t ws_size,
                              hipStream_t stream)
{
    const float* X    = (const float*)d_in[0];
    const float* XC   = (const float*)d_in[1];
    const float* fcW1 = (const float*)d_in[2];
    const float* fcb1 = (const float*)d_in[3];
    const float* fcW2 = (const float*)d_in[4];
    const float* fcb2 = (const float*)d_in[5];
    const float* fRW1 = (const float*)d_in[6];
    const float* fRb1 = (const float*)d_in[7];
    const float* fRW2 = (const float*)d_in[8];
    const float* fRb2 = (const float*)d_in[9];
    const float* T1W1 = (const float*)d_in[10];
    const float* T1b1 = (const float*)d_in[11];
    const float* T1W2 = (const float*)d_in[12];
    const float* T1b2 = (const float*)d_in[13];
    const float* T2W1 = (const float*)d_in[14];
    const float* T2b1 = (const float*)d_in[15];
    const float* T2W2 = (const float*)d_in[16];
    const float* T2b2 = (const float*)d_in[17];
    float* OUT = (float*)d_out;

    char* w = (char*)d_ws;
    uint2* VMK   = (uint2*)w;      w += (size_t)NT * NS * NH * 8;   // 186.9 MB
    float4* PSE  = (float4*)w;     w += (size_t)NT * NS * 16;       // 23.4 MB
    float* BASE1 = (float*)w;      w += (size_t)NS * HID * 4;
    float* BASE2 = (float*)w;      w += (size_t)NS * HID * 4;
    float* P8    = (float*)w;      w += (size_t)NS * NH * 8 * 4;
    float* RKGA  = (float*)w;      w += (size_t)NS * NH * 16 * 4;
    _Float16* W2H = (_Float16*)w;  w += 48 * HID * 2;
    float* A1    = (float*)w;      w += HID * 4;
    float* C0    = (float*)w;      w += HID * 4;
    float* C1    = (float*)w;      w += HID * 4;
    float* C2    = (float*)w;      w += HID * 4;
    (void)ws_size; (void)in_sizes; (void)n_in; (void)out_size;

    k_pack<<<dim3(1), dim3(256), 0, stream>>>(T1W1, T2W1, T1W2, T2W2, A1, C0, C1, C2, W2H);
    k_basin<<<dim3(NS), dim3(256), 0, stream>>>(XC, fcW1, fcb1, fcW2, fcb2,
                                                fRW1, fRb1, fRW2, fRb2,
                                                T1W1, T1b1, T2W1, T2b1,
                                                P8, RKGA, BASE1, BASE2);
    k_mlp<<<dim3(125, 46), dim3(256), 0, stream>>>(
        X, BASE1, BASE2, A1, C0, C1, C2, W2H, T1b2, T2b2, VMK, PSE);
    k_scan<<<dim3(NS / 4), dim3(64), 0, stream>>>(VMK, PSE, P8, RKGA, OUT);
}

// Round 6
// 652.726 us; speedup vs baseline: 12.3309x; 1.0757x over previous
//
#include <hip/hip_runtime.h>
#include <math.h>

#define NT 730
#define NS 2000
#define NH 16
#define NG 32
#define NR 15
#define HID 256

// 2*log2(e): pre-folded into BASE1/BASE2/A1/C0..C2 so tanh arg is a bare fma
// and tanh(x) = 1 - 2*rcp(exp2(y)+1), y = SC*x.
#define SC 2.885390081777927f
#define INV6 0.16666666666666666f

typedef _Float16 f16x8 __attribute__((ext_vector_type(8)));
typedef __fp16 fp16v2 __attribute__((ext_vector_type(2)));   // cvt_pkrtz native return type
typedef float f32x4 __attribute__((ext_vector_type(4)));

__device__ __forceinline__ float tanh_pre(float y) {   // y = SC * x
    float e = __builtin_amdgcn_exp2f(y);
    float r = __builtin_amdgcn_rcpf(e + 1.f);
    return fmaf(-2.f, r, 1.f);
}
__device__ __forceinline__ float fast_tanh(float x) { return tanh_pre(x * SC); }
__device__ __forceinline__ float sigmoidf_(float x) { return 1.f / (1.f + __expf(-x)); }

__device__ __forceinline__ float4 fma4(float s, float4 a, float4 b) {
    return make_float4(fmaf(s, a.x, b.x), fmaf(s, a.y, b.y), fmaf(s, a.z, b.z), fmaf(s, a.w, b.w));
}
// tanh each of 8 args, pack to f16x8 via pkrtz (no allocas anywhere).
__device__ __forceinline__ f16x8 tanh8(float4 lo, float4 hi) {
    union { fp16v2 h[4]; f16x8 v; } u;
    u.h[0] = __builtin_amdgcn_cvt_pkrtz(tanh_pre(lo.x), tanh_pre(lo.y));
    u.h[1] = __builtin_amdgcn_cvt_pkrtz(tanh_pre(lo.z), tanh_pre(lo.w));
    u.h[2] = __builtin_amdgcn_cvt_pkrtz(tanh_pre(hi.x), tanh_pre(hi.y));
    u.h[3] = __builtin_amdgcn_cvt_pkrtz(tanh_pre(hi.z), tanh_pre(hi.w));
    return u.v;
}

// ---------------------------------------------------------------------------
// k_pack: gather small weight slices; coefficient columns pre-scaled by SC.
//   W2H epilogue folding: cols 0..31 (vi,vk) x1/6 (hsig -> clamp);
//   cols 32..47 (vm) xSC (exp(2z) -> exp2).
// ---------------------------------------------------------------------------
__global__ __launch_bounds__(256) void k_pack(
    const float* __restrict__ T1W1, const float* __restrict__ T2W1,
    const float* __restrict__ T1W2, const float* __restrict__ T2W2,
    float* __restrict__ A1, float* __restrict__ C0, float* __restrict__ C1,
    float* __restrict__ C2, _Float16* __restrict__ W2H)
{
    int k = threadIdx.x;
    A1[k] = SC * T1W1[k * (1 + NG)];
    C0[k] = SC * T2W1[k * (3 + NG)];
    C1[k] = SC * T2W1[k * (3 + NG) + 1];
    C2[k] = SC * T2W1[k * (3 + NG) + 2];
    for (int c = 0; c < 48; ++c) {
        float w = (c < 32) ? (INV6 * T1W2[c * HID + k]) : (SC * T2W2[(c - 32) * HID + k]);
        W2H[c * HID + k] = (_Float16)w;
    }
}

// ---------------------------------------------------------------------------
// k_basin v2: 4 basins per block -> every weight read amortized x4.
// ---------------------------------------------------------------------------
__global__ __launch_bounds__(256) void k_basin(
    const float* __restrict__ XC,
    const float* __restrict__ fcW1, const float* __restrict__ fcb1,
    const float* __restrict__ fcW2, const float* __restrict__ fcb2,
    const float* __restrict__ fRW1, const float* __restrict__ fRb1,
    const float* __restrict__ fRW2, const float* __restrict__ fRb2,
    const float* __restrict__ T1W1, const float* __restrict__ T1b1,
    const float* __restrict__ T2W1, const float* __restrict__ T2b1,
    float* __restrict__ P8, float* __restrict__ RKGA,
    float* __restrict__ BASE1, float* __restrict__ BASE2)
{
    const int s0 = blockIdx.x * 4, tid = threadIdx.x;
    __shared__ float xcs[4][NG];
    __shared__ float h[4][HID], hR[4][HID];
    __shared__ float wbuf[4][10 * NH], wRbuf[4][NH * NR];
    __shared__ float gav[4][NH];

    if (tid < 128) xcs[tid >> 5][tid & 31] = XC[(s0 + (tid >> 5)) * NG + (tid & 31)];
    __syncthreads();

    // Phase A: k = tid; 4 basins per thread, weight rows read once.
    {
        float ab0 = fcb1[tid], ab1 = ab0, ab2 = ab0, ab3 = ab0;
        float rb0 = fRb1[tid], rb1 = rb0, rb2 = rb0, rb3 = rb0;
        const float4* w4  = (const float4*)(fcW1 + tid * NG);
        const float4* wR4 = (const float4*)(fRW1 + tid * NG);
#pragma unroll
        for (int g = 0; g < NG / 4; ++g) {
            float4 wv = w4[g], rv = wR4[g];
            float4 x0 = *(const float4*)&xcs[0][g * 4];
            float4 x1 = *(const float4*)&xcs[1][g * 4];
            float4 x2 = *(const float4*)&xcs[2][g * 4];
            float4 x3 = *(const float4*)&xcs[3][g * 4];
            ab0 += x0.x*wv.x + x0.y*wv.y + x0.z*wv.z + x0.w*wv.w;
            ab1 += x1.x*wv.x + x1.y*wv.y + x1.z*wv.z + x1.w*wv.w;
            ab2 += x2.x*wv.x + x2.y*wv.y + x2.z*wv.z + x2.w*wv.w;
            ab3 += x3.x*wv.x + x3.y*wv.y + x3.z*wv.z + x3.w*wv.w;
            rb0 += x0.x*rv.x + x0.y*rv.y + x0.z*rv.z + x0.w*rv.w;
            rb1 += x1.x*rv.x + x1.y*rv.y + x1.z*rv.z + x1.w*rv.w;
            rb2 += x2.x*rv.x + x2.y*rv.y + x2.z*rv.z + x2.w*rv.w;
            rb3 += x3.x*rv.x + x3.y*rv.y + x3.z*rv.z + x3.w*rv.w;
        }
        h[0][tid] = fast_tanh(ab0); h[1][tid] = fast_tanh(ab1);
        h[2][tid] = fast_tanh(ab2); h[3][tid] = fast_tanh(ab3);
        hR[0][tid] = fast_tanh(rb0); hR[1][tid] = fast_tanh(rb1);
        hR[2][tid] = fast_tanh(rb2); hR[3][tid] = fast_tanh(rb3);

        float b10 = T1b1[tid], b11 = b10, b12 = b10, b13 = b10;
        float b20 = T2b1[tid], b21 = b20, b22 = b20, b23 = b20;
        const float* w1 = T1W1 + tid * (1 + NG) + 1;
        const float* w2 = T2W1 + tid * (3 + NG) + 3;
#pragma unroll 8
        for (int g = 0; g < NG; ++g) {
            float w1g = w1[g], w2g = w2[g];
            float x0 = xcs[0][g], x1 = xcs[1][g], x2 = xcs[2][g], x3 = xcs[3][g];
            b10 = fmaf(x0, w1g, b10); b11 = fmaf(x1, w1g, b11);
            b12 = fmaf(x2, w1g, b12); b13 = fmaf(x3, w1g, b13);
            b20 = fmaf(x0, w2g, b20); b21 = fmaf(x1, w2g, b21);
            b22 = fmaf(x2, w2g, b22); b23 = fmaf(x3, w2g, b23);
        }
        BASE1[(size_t)(s0 + 0) * HID + tid] = SC * b10;
        BASE1[(size_t)(s0 + 1) * HID + tid] = SC * b11;
        BASE1[(size_t)(s0 + 2) * HID + tid] = SC * b12;
        BASE1[(size_t)(s0 + 3) * HID + tid] = SC * b13;
        BASE2[(size_t)(s0 + 0) * HID + tid] = SC * b20;
        BASE2[(size_t)(s0 + 1) * HID + tid] = SC * b21;
        BASE2[(size_t)(s0 + 2) * HID + tid] = SC * b22;
        BASE2[(size_t)(s0 + 3) * HID + tid] = SC * b23;
    }
    __syncthreads();

    // Phase B: second layers; weight row read once, 4 basin accumulators.
    if (tid < 10 * NH) {
        float a0 = fcb2[tid], a1 = a0, a2 = a0, a3 = a0;
        const float4* w4 = (const float4*)(fcW2 + tid * HID);
        for (int k = 0; k < HID / 4; ++k) {
            float4 wv = w4[k];
            float4 h0 = *(const float4*)&h[0][k * 4];
            float4 h1 = *(const float4*)&h[1][k * 4];
            float4 h2 = *(const float4*)&h[2][k * 4];
            float4 h3 = *(const float4*)&h[3][k * 4];
            a0 += h0.x*wv.x + h0.y*wv.y + h0.z*wv.z + h0.w*wv.w;
            a1 += h1.x*wv.x + h1.y*wv.y + h1.z*wv.z + h1.w*wv.w;
            a2 += h2.x*wv.x + h2.y*wv.y + h2.z*wv.z + h2.w*wv.w;
            a3 += h3.x*wv.x + h3.y*wv.y + h3.z*wv.z + h3.w*wv.w;
        }
        wbuf[0][tid] = a0; wbuf[1][tid] = a1; wbuf[2][tid] = a2; wbuf[3][tid] = a3;
    }
    if (tid < NH * NR) {
        float a0 = fRb2[tid], a1 = a0, a2 = a0, a3 = a0;
        const float4* w4 = (const float4*)(fRW2 + tid * HID);
        for (int k = 0; k < HID / 4; ++k) {
            float4 wv = w4[k];
            float4 h0 = *(const float4*)&hR[0][k * 4];
            float4 h1 = *(const float4*)&hR[1][k * 4];
            float4 h2 = *(const float4*)&hR[2][k * 4];
            float4 h3 = *(const float4*)&hR[3][k * 4];
            a0 += h0.x*wv.x + h0.y*wv.y + h0.z*wv.z + h0.w*wv.w;
            a1 += h1.x*wv.x + h1.y*wv.y + h1.z*wv.z + h1.w*wv.w;
            a2 += h2.x*wv.x + h2.y*wv.y + h2.z*wv.z + h2.w*wv.w;
            a3 += h3.x*wv.x + h3.y*wv.y + h3.z*wv.z + h3.w*wv.w;
        }
        wRbuf[0][tid] = a0; wRbuf[1][tid] = a1; wRbuf[2][tid] = a2; wRbuf[3][tid] = a3;
    }
    __syncthreads();

    if (tid < 64) {
        int b = tid >> 4, hh = tid & 15;
        const float* wb = wbuf[b];
        float mx = -1e30f;
        for (int i = 0; i < NH; ++i) mx = fmaxf(mx, wb[6 * NH + i]);
        float sum = 0.f;
        for (int i = 0; i < NH; ++i) sum += expf(wb[6 * NH + i] - mx);
        gav[b][hh] = expf(wb[6 * NH + hh] - mx) / sum;

        float* p = P8 + (size_t)((s0 + b) * NH + hh) * 8;
        p[0] = sigmoidf_(wb[1 * NH + hh]);
        p[1] = sigmoidf_(wb[2 * NH + hh]);
        p[2] = sigmoidf_(wb[3 * NH + hh]);
        p[3] = sigmoidf_(wb[4 * NH + hh]) * 0.1f;
        p[4] = expf(wb[5 * NH + hh]) * 2.f;
        p[5] = fmaxf(wb[7 * NH + hh], 0.f);
        p[6] = fmaxf(wb[8 * NH + hh], 0.f);
        p[7] = fmaxf(wb[9 * NH + hh], 0.f);
    }
    __syncthreads();

    for (int it = tid; it < 4 * NH * NR; it += 256) {
        int b = it / (NH * NR), r = it % (NH * NR);
        int hh = r / NR, j = r % NR;
        RKGA[(size_t)((s0 + b) * NH + hh) * 16 + (NR - 1 - j)] =
            gav[b][hh] * fmaxf(wRbuf[b][hh * NR + j], 0.f);
    }
}

// ---------------------------------------------------------------------------
// PSE helper (vp partition).
// ---------------------------------------------------------------------------
__device__ __forceinline__ void store_pse(float4* __restrict__ PSE, long m, float2 pe, float2 t12) {
    float P = pe.x, E = pe.y, T1 = t12.x, T2 = t12.y;
    float den = T2 - T1;
    float ratio = (T1 + T2) / ((den == 0.f) ? 1.f : den);
    ratio = fminf(fmaxf(ratio, -1.f), 1.f);
    if ((T1 >= 0.f) || (T2 <= 0.f)) ratio = 0.f;
    float vp = 1.f - acosf(ratio) * (1.f / 3.1415f);
    if (T1 >= 0.f) vp = 1.f;
    if (T2 <= 0.f) vp = 0.f;
    PSE[m] = make_float4(P * (1.f - vp), P * vp, E, 0.f);
}

// ---------------------------------------------------------------------------
// k_mlp v5: t-reuse tiling, ZERO private arrays (R4's tcl[quad] dynamic index
//   forced the tile arrays into LDS scratch: 8 KB LDS + 414k bank-conflict
//   cycles). All tile state in named vars; PSE index computed directly.
//   Epilogue constants folded into W2H/bias: vi/vk = clamp(acc), vm = exp2(acc).
// ---------------------------------------------------------------------------
__global__ __launch_bounds__(256) void k_mlp(
    const float* __restrict__ X,
    const float* __restrict__ BASE1, const float* __restrict__ BASE2,
    const float* __restrict__ A1, const float* __restrict__ C0,
    const float* __restrict__ C1, const float* __restrict__ C2,
    const _Float16* __restrict__ W2H,
    const float* __restrict__ T1b2, const float* __restrict__ T2b2,
    uint2* __restrict__ VMK, float4* __restrict__ PSE)
{
    const int tid = threadIdx.x;
    const int wave = tid >> 6, lane = tid & 63;
    const int quad = lane >> 4, ml = lane & 15;
    const int s0 = blockIdx.x * 16;
    const int t0 = blockIdx.y * 16 + wave * 4;
    const int srow = s0 + ml;

    const int tc0 = (t0 < NT) ? t0 : (NT - 1);
    const int tc1 = (t0 + 1 < NT) ? t0 + 1 : (NT - 1);
    const int tc2 = (t0 + 2 < NT) ? t0 + 2 : (NT - 1);
    const int tc3 = (t0 + 3 < NT) ? t0 + 3 : (NT - 1);

    const float* xr0 = X + ((long)tc0 * NS + srow) * 6;
    const float* xr1 = X + ((long)tc1 * NS + srow) * 6;
    const float* xr2 = X + ((long)tc2 * NS + srow) * 6;
    const float* xr3 = X + ((long)tc3 * NS + srow) * 6;
    float2 tt0 = *(const float2*)(xr0 + 2), rl0 = *(const float2*)(xr0 + 4);
    float2 tt1 = *(const float2*)(xr1 + 2), rl1 = *(const float2*)(xr1 + 4);
    float2 tt2 = *(const float2*)(xr2 + 2), rl2 = *(const float2*)(xr2 + 4);
    float2 tt3 = *(const float2*)(xr3 + 2), rl3 = *(const float2*)(xr3 + 4);

    const float bvi = fmaf(T1b2[ml], INV6, 0.5f);
    const float bvk = fmaf(T1b2[NH + ml], INV6, 0.5f);
    const float bvm = SC * T2b2[ml];
    f32x4 ac0_0 = {bvi, bvi, bvi, bvi}, ac0_1 = ac0_0, ac0_2 = ac0_0, ac0_3 = ac0_0;
    f32x4 ac1_0 = {bvk, bvk, bvk, bvk}, ac1_1 = ac1_0, ac1_2 = ac1_0, ac1_3 = ac1_0;
    f32x4 ac2_0 = {bvm, bvm, bvm, bvm}, ac2_1 = ac2_0, ac2_2 = ac2_0, ac2_3 = ac2_0;

    const float* b1p = BASE1 + (size_t)srow * HID;
    const float* b2p = BASE2 + (size_t)srow * HID;
    const _Float16* wvi = W2H + (size_t)ml * HID;
    const _Float16* wvk = W2H + (size_t)(NH + ml) * HID;
    const _Float16* wvm = W2H + (size_t)(2 * NH + ml) * HID;

#pragma unroll 2
    for (int ks = 0; ks < 8; ++ks) {
        const int kb = ks * 32 + quad * 8;
        float4 a1lo = *(const float4*)(A1 + kb), a1hi = *(const float4*)(A1 + kb + 4);
        float4 c0lo = *(const float4*)(C0 + kb), c0hi = *(const float4*)(C0 + kb + 4);
        float4 c1lo = *(const float4*)(C1 + kb), c1hi = *(const float4*)(C1 + kb + 4);
        float4 c2lo = *(const float4*)(C2 + kb), c2hi = *(const float4*)(C2 + kb + 4);
        float4 b1lo = *(const float4*)(b1p + kb), b1hi = *(const float4*)(b1p + kb + 4);
        float4 b2lo = *(const float4*)(b2p + kb), b2hi = *(const float4*)(b2p + kb + 4);
        f16x8 Bvi = *(const f16x8*)(wvi + kb);
        f16x8 Bvk = *(const f16x8*)(wvk + kb);
        f16x8 Bvm = *(const f16x8*)(wvm + kb);

#define DO_TILE(RL, TT, AC0, AC1, AC2) { \
        f16x8 Af1 = tanh8(fma4(RL.y, a1lo, b1lo), fma4(RL.y, a1hi, b1hi)); \
        float4 qlo = fma4(TT.y, c2lo, fma4(TT.x, c1lo, fma4(RL.x, c0lo, b2lo))); \
        float4 qhi = fma4(TT.y, c2hi, fma4(TT.x, c1hi, fma4(RL.x, c0hi, b2hi))); \
        f16x8 Af2 = tanh8(qlo, qhi); \
        AC0 = __builtin_amdgcn_mfma_f32_16x16x32_f16(Af1, Bvi, AC0, 0, 0, 0); \
        AC1 = __builtin_amdgcn_mfma_f32_16x16x32_f16(Af1, Bvk, AC1, 0, 0, 0); \
        AC2 = __builtin_amdgcn_mfma_f32_16x16x32_f16(Af2, Bvm, AC2, 0, 0, 0); }

        DO_TILE(rl0, tt0, ac0_0, ac1_0, ac2_0)
        DO_TILE(rl1, tt1, ac0_1, ac1_1, ac2_1)
        DO_TILE(rl2, tt2, ac0_2, ac1_2, ac2_2)
        DO_TILE(rl3, tt3, ac0_3, ac1_3, ac2_3)
#undef DO_TILE
    }

    // Epilogue: C layout col(ml)=channel, row = quad*4+rg = s-offset in tile.
#define EPI(TC, AC0, AC1, AC2) { \
    long rowbase = (long)TC * NS + s0 + quad * 4; \
    _Pragma("unroll") \
    for (int rg = 0; rg < 4; ++rg) { \
        float vi = fminf(fmaxf(AC0[rg], 0.f), 1.f); \
        float vk = fminf(fmaxf(AC1[rg], 0.f), 1.f); \
        float vm = __builtin_amdgcn_exp2f(AC2[rg]); \
        unsigned pk = (unsigned)(vi * 65535.f + 0.5f) | ((unsigned)(vk * 65535.f + 0.5f) << 16); \
        VMK[(rowbase + rg) * NH + ml] = make_uint2(pk, __float_as_uint(vm)); \
    } }

    EPI(tc0, ac0_0, ac1_0, ac2_0)
    EPI(tc1, ac0_1, ac1_1, ac2_1)
    EPI(tc2, ac0_2, ac1_2, ac2_2)
    EPI(tc3, ac0_3, ac1_3, ac2_3)
#undef EPI

    // PSE: one store per lane; t-index computed directly (no dynamic array idx).
    {
        int tq = t0 + quad; if (tq >= NT) tq = NT - 1;
        const float* xq = X + ((long)tq * NS + srow) * 6;
        float2 peq = *(const float2*)xq;
        float2 ttq = *(const float2*)(xq + 2);
        store_pse(PSE, (long)tq * NS + srow, peq, ttq);
    }
}

// ---------------------------------------------------------------------------
// k_scan: 730-step bucket scan + fused causal conv (taps*ga) + h-sum.
//   One wave = 4 basins x 16 buckets. Mod-14 sample ring, prefetch depth 14.
// ---------------------------------------------------------------------------
__global__ __launch_bounds__(64) void k_scan(
    const uint2* __restrict__ VMK, const float4* __restrict__ PSE,
    const float* __restrict__ P8, const float* __restrict__ RKGA,
    float* __restrict__ OUT)
{
    int lane = threadIdx.x;
    int s = blockIdx.x * 4 + (lane >> 4);
    int hh = lane & 15;
    size_t ch = (size_t)s * NH + hh;

    const float4* pp = (const float4*)(P8 + (size_t)ch * 8);
    float4 pa = pp[0], pb4 = pp[1];
    float k1 = pa.x, k2 = pa.y, k23 = pa.z, k3 = pa.w;
    float gl = pb4.x, qb = pb4.y, ge1 = pb4.z, ge2 = pb4.w;

    float rk[16];
    {
        const float4* rp = (const float4*)(RKGA + (size_t)ch * 16);
#pragma unroll
        for (int i = 0; i < 4; ++i) {
            float4 v = rp[i];
            rk[4 * i] = v.x; rk[4 * i + 1] = v.y; rk[4 * i + 2] = v.z; rk[4 * i + 3] = v.w;
        }
    }

    float S0 = 0.f, Sv = 0.f, S2 = 0.f, S3 = 0.f;
    float qr[14];
#pragma unroll
    for (int i = 0; i < 14; ++i) qr[i] = 0.f;

    uint2 vb[14]; float4 pbf[14];
#pragma unroll
    for (int i = 0; i < 14; ++i) {
        vb[i] = VMK[(size_t)i * (NS * NH) + ch];
        pbf[i] = PSE[(size_t)i * NS + s];
    }

    int t = 0;
#define SBODY(I) { \
    uint2 v = vb[I]; float4 ps = pbf[I]; \
    int t2 = t + 14; if (t2 > NT - 1) t2 = NT - 1; \
    vb[I] = VMK[(size_t)t2 * (NS * NH) + ch]; \
    pbf[I] = PSE[(size_t)t2 * NS + s]; \
    float vi = (float)(v.x & 0xffffu) * (1.f / 65535.f); \
    float vk = (float)(v.x >> 16) * (1.f / 65535.f); \
    float vm = __uint_as_float(v.y); \
    float Ps = ps.x, Pl = ps.y, E = ps.z; \
    float H0 = S0 + Ps; \
    float qSm = fminf(H0, vm); S0 = H0 - qSm; \
    float Hv = fmaxf(Sv + Pl * (1.f - vi) - E * ge1, 0.f); \
    float qv = Sv * vk; Sv = Hv - qv; \
    float H2 = fmaxf(S2 + qSm + qv - E * ge2 + Pl * vi, 0.f); \
    float x1 = H2 - gl; \
    float Q1 = (x1 > 0.f) ? __expf(k1 * __logf(x1)) : 0.f; \
    float q2 = fminf(H2, gl) * k2; \
    float Q2 = q2 * (1.f - k23); \
    float H3 = S3 + q2 * k23; \
    float Q3 = H3 * k3 + qb; \
    S2 = H2 - Q1 - q2; S3 = H3 - Q3; \
    float qt = Q1 + Q2 + Q3; \
    float y = qt * rk[0]; \
    _Pragma("unroll") for (int d = 1; d <= 14; ++d) y += qr[((I) + 14 - d) % 14] * rk[d]; \
    qr[I] = qt; \
    y += __shfl_xor(y, 1); y += __shfl_xor(y, 2); \
    y += __shfl_xor(y, 4); y += __shfl_xor(y, 8); \
    if (hh == 0) OUT[(size_t)t * NS + s] = y; \
    ++t; }

    for (int tb = 0; tb < 52; ++tb) {          // 52 * 14 = 728 steps
        SBODY(0) SBODY(1) SBODY(2) SBODY(3) SBODY(4) SBODY(5) SBODY(6)
        SBODY(7) SBODY(8) SBODY(9) SBODY(10) SBODY(11) SBODY(12) SBODY(13)
    }
    SBODY(0) SBODY(1)                          // steps 728, 729
#undef SBODY
}

// ---------------------------------------------------------------------------
extern "C" void kernel_launch(void* const* d_in, const int* in_sizes, int n_in,
                              void* d_out, int out_size, void* d_ws, size_t ws_size,
                              hipStream_t stream)
{
    const float* X    = (const float*)d_in[0];
    const float* XC   = (const float*)d_in[1];
    const float* fcW1 = (const float*)d_in[2];
    const float* fcb1 = (const float*)d_in[3];
    const float* fcW2 = (const float*)d_in[4];
    const float* fcb2 = (const float*)d_in[5];
    const float* fRW1 = (const float*)d_in[6];
    const float* fRb1 = (const float*)d_in[7];
    const float* fRW2 = (const float*)d_in[8];
    const float* fRb2 = (const float*)d_in[9];
    const float* T1W1 = (const float*)d_in[10];
    const float* T1b1 = (const float*)d_in[11];
    const float* T1W2 = (const float*)d_in[12];
    const float* T1b2 = (const float*)d_in[13];
    const float* T2W1 = (const float*)d_in[14];
    const float* T2b1 = (const float*)d_in[15];
    const float* T2W2 = (const float*)d_in[16];
    const float* T2b2 = (const float*)d_in[17];
    float* OUT = (float*)d_out;

    char* w = (char*)d_ws;
    uint2* VMK   = (uint2*)w;      w += (size_t)NT * NS * NH * 8;   // 186.9 MB
    float4* PSE  = (float4*)w;     w += (size_t)NT * NS * 16;       // 23.4 MB
    float* BASE1 = (float*)w;      w += (size_t)NS * HID * 4;
    float* BASE2 = (float*)w;      w += (size_t)NS * HID * 4;
    float* P8    = (float*)w;      w += (size_t)NS * NH * 8 * 4;
    float* RKGA  = (float*)w;      w += (size_t)NS * NH * 16 * 4;
    _Float16* W2H = (_Float16*)w;  w += 48 * HID * 2;
    float* A1    = (float*)w;      w += HID * 4;
    float* C0    = (float*)w;      w += HID * 4;
    float* C1    = (float*)w;      w += HID * 4;
    float* C2    = (float*)w;      w += HID * 4;
    (void)ws_size; (void)in_sizes; (void)n_in; (void)out_size;

    k_pack<<<dim3(1), dim3(256), 0, stream>>>(T1W1, T2W1, T1W2, T2W2, A1, C0, C1, C2, W2H);
    k_basin<<<dim3(NS / 4), dim3(256), 0, stream>>>(XC, fcW1, fcb1, fcW2, fcb2,
                                                    fRW1, fRb1, fRW2, fRb2,
                                                    T1W1, T1b1, T2W1, T2b1,
                                                    P8, RKGA, BASE1, BASE2);
    k_mlp<<<dim3(125, 46), dim3(256), 0, stream>>>(
        X, BASE1, BASE2, A1, C0, C1, C2, W2H, T1b2, T2b2, VMK, PSE);
    k_scan<<<dim3(NS / 4), dim3(64), 0, stream>>>(VMK, PSE, P8, RKGA, OUT);
}